// Round 8
// baseline (446.913 us; speedup 1.0000x reference)
//
#include <hip/hip_runtime.h>

// ---------- model dims ----------
#define NB   32
#define TT   46
#define RNN  128
#define CDIM 24
#define GD   256
#define GIN  180

typedef __attribute__((ext_vector_type(8))) short  bf16x8;
typedef __attribute__((ext_vector_type(4))) short  s16x4;
typedef __attribute__((ext_vector_type(8))) unsigned short u16x8;
typedef __attribute__((ext_vector_type(4))) float  f32x4;

__device__ __forceinline__ unsigned short f2bf(float v) {
    unsigned u = __float_as_uint(v);
    u = u + 0x7fffu + ((u >> 16) & 1u);   // RNE
    return (unsigned short)(u >> 16);
}

// ---------------- LSTM body (1024 threads: 2 threads per gate, k-split) ----------------
// per-thread weights: 16+64 floats = 80 VGPR -> no spill at 128 cap
__device__ __forceinline__ void lstm_body(
    const int* __restrict__ q, const float* __restrict__ embW,
    const float* __restrict__ Wih, const float* __restrict__ Whh,
    const float* __restrict__ bih, const float* __restrict__ bhh,
    float* __restrict__ qf, int n)
{
    const int tid = threadIdx.x;          // 0..1023
    const int g = tid >> 1, h = tid & 1;  // gate, k-half
    __shared__ __align__(16) float xs[32], hs[RNN];
    __shared__ float zg[512];
    f32x4 wih[4], whh[16];
    {
        const f32x4* wp = (const f32x4*)(Wih + g * 32 + h * 16);
#pragma unroll
        for (int j = 0; j < 4; j++) wih[j] = wp[j];
        const f32x4* hp = (const f32x4*)(Whh + g * RNN + h * 64);
#pragma unroll
        for (int j = 0; j < 16; j++) whh[j] = hp[j];
    }
    const float bias = bih[g] + bhh[g];
    float creg = 0.f;
    if (tid < RNN) hs[tid] = 0.f;
    float xr = (tid < 32) ? embW[q[n * TT] * 32 + tid] : 0.f;
    __syncthreads();
    for (int t = 0; t < TT; t++) {
        if (tid < 32) xs[tid] = xr;
        __syncthreads();           // xs ready, hs ready
        if (tid < 32 && t + 1 < TT) xr = embW[q[n * TT + t + 1] * 32 + tid];
        const f32x4* x4 = (const f32x4*)xs + (h << 2);   // h*16 floats
        const f32x4* h4 = (const f32x4*)hs + (h << 4);   // h*64 floats
        f32x4 a0 = {0.f, 0.f, 0.f, 0.f}, a1 = a0, a2 = a0, a3 = a0;
        a0 += wih[0] * x4[0]; a1 += wih[1] * x4[1];
        a2 += wih[2] * x4[2]; a3 += wih[3] * x4[3];
#pragma unroll
        for (int j = 0; j < 16; j += 4) {
            a0 += whh[j] * h4[j];         a1 += whh[j + 1] * h4[j + 1];
            a2 += whh[j + 2] * h4[j + 2]; a3 += whh[j + 3] * h4[j + 3];
        }
        f32x4 a = (a0 + a1) + (a2 + a3);
        float p = (a[0] + a[1]) + (a[2] + a[3]);
        p += __shfl_xor(p, 1, 64);        // combine the two k-halves
        if (h == 0) zg[g] = p + bias;
        __syncthreads();
        if (tid < RNN) {
            float ig = 1.f / (1.f + __expf(-zg[tid]));
            float fg = 1.f / (1.f + __expf(-zg[RNN + tid]));
            float gg = tanhf(zg[2 * RNN + tid]);
            float og = 1.f / (1.f + __expf(-zg[3 * RNN + tid]));
            float cn = fg * creg + ig * gg;
            creg = cn;
            hs[tid] = og * tanhf(cn);
        }
        __syncthreads();
    }
    if (tid < RNN) qf[n * RNN + tid] = hs[tid];
}

// ---------------- tiled conv 3x3 s2 p1 body ----------------
template<int CIN, int TILE, bool BNIN, int BS>
__device__ __forceinline__ void conv_body(
    const float* __restrict__ in, const float* __restrict__ Wg,
    const float* __restrict__ bias,
    const float* __restrict__ pstats, const float* __restrict__ pg,
    const float* __restrict__ pb, float pinvM,
    float* __restrict__ out, float* __restrict__ stats,
    int HIN, int WIN, int HO, int WO, int tilesX, int bx)
{
    constexpr int NPIX = TILE * TILE;
    constexpr int CPG  = BS / NPIX;
    constexpr int COPT = 24 / CPG;
    constexpr int WPB  = BS / 64;
    constexpr int WPC  = NPIX / 64;
    constexpr int S  = 2 * TILE + 1;
    constexpr int SP = S + 1;
    __shared__ float in_t[CIN][S][SP];
    __shared__ float r1s[WPB][COPT], r2s[WPB][COPT];
    __shared__ float sc[CIN], sh[CIN];
    const int tid = threadIdx.x;
    const int tx = bx % tilesX;
    const int ty = (bx / tilesX) % tilesX;
    const int n  = bx / (tilesX * tilesX);

    if (BNIN) {
        if (tid < CIN) {
            float mu  = pstats[2 * tid] * pinvM;
            float var = pstats[2 * tid + 1] * pinvM - mu * mu;
            float rs  = rsqrtf(var + 1e-5f);
            sc[tid] = rs * pg[tid];
            sh[tid] = pb[tid] - mu * rs * pg[tid];
        }
        __syncthreads();
    }
    const int iy0 = ty * 2 * TILE - 1, ix0 = tx * 2 * TILE - 1;
    for (int idx = tid; idx < CIN * S * S; idx += BS) {
        int ci = idx / (S * S), r = idx % (S * S);
        int ry = r / S, rx = r % S;
        int gy = iy0 + ry, gx = ix0 + rx;
        float v = 0.f;
        if ((unsigned)gy < (unsigned)HIN && (unsigned)gx < (unsigned)WIN) {
            v = in[((size_t)(n * CIN + ci) * HIN + gy) * WIN + gx];
            if (BNIN) v = fmaxf(v * sc[ci] + sh[ci], 0.f);
        }
        in_t[ci][ry][rx] = v;
    }
    __syncthreads();

    const int p   = tid % NPIX;
    const int co0 = __builtin_amdgcn_readfirstlane((tid / NPIX) * COPT);
    const int ly  = (p / TILE) * 2, lx = (p % TILE) * 2;
    float acc[COPT];
#pragma unroll
    for (int c = 0; c < COPT; c++) acc[c] = bias[co0 + c];
    for (int ci = 0; ci < CIN; ci++) {
#pragma unroll
        for (int ky = 0; ky < 3; ky++) {
            const float* row = &in_t[ci][ly + ky][lx];
#pragma unroll
            for (int kx = 0; kx < 3; kx++) {
                float v = row[kx];
#pragma unroll
                for (int c = 0; c < COPT; c++)
                    acc[c] += v * Wg[(((co0 + c) * CIN + ci) * 3 + ky) * 3 + kx];
            }
        }
    }
    const int oy = ty * TILE + p / TILE, ox = tx * TILE + p % TILE;
#pragma unroll
    for (int c = 0; c < COPT; c++)
        out[((size_t)(n * 24 + co0 + c) * HO + oy) * WO + ox] = acc[c];

    const int lane = tid & 63, wv = tid >> 6;
#pragma unroll
    for (int c = 0; c < COPT; c++) {
        float s1 = acc[c], s2 = acc[c] * acc[c];
#pragma unroll
        for (int off = 1; off < 64; off <<= 1) {
            s1 += __shfl_xor(s1, off, 64);
            s2 += __shfl_xor(s2, off, 64);
        }
        if (lane == 0) { r1s[wv][c] = s1; r2s[wv][c] = s2; }
    }
    __syncthreads();
    if (tid < 24) {
        int cg = tid / COPT, slot = tid % COPT;
        float t1 = 0.f, t2 = 0.f;
#pragma unroll
        for (int u = 0; u < WPC; u++) { t1 += r1s[cg * WPC + u][slot]; t2 += r2s[cg * WPC + u][slot]; }
        atomicAdd(&stats[tid * 2],     t1);
        atomicAdd(&stats[tid * 2 + 1], t2);
    }
}

template<int CIN, int TILE, bool BNIN>
__global__ __launch_bounds__(256) void conv_tiled(
    const float* __restrict__ in, const float* __restrict__ Wg,
    const float* __restrict__ bias,
    const float* __restrict__ pstats, const float* __restrict__ pg,
    const float* __restrict__ pb, float pinvM,
    float* __restrict__ out, float* __restrict__ stats,
    int HIN, int WIN, int HO, int WO, int tilesX)
{
    conv_body<CIN, TILE, BNIN, 256>(in, Wg, bias, pstats, pg, pb, pinvM,
                                    out, stats, HIN, WIN, HO, WO, tilesX, blockIdx.x);
}

// ---------------- merged front: lstm (0-31) + conv0 (32-543) + cvt (544-591) ----------------
__global__ __launch_bounds__(1024, 4) void fused_front(
    const int* __restrict__ q, const float* __restrict__ embW,
    const float* __restrict__ Wih, const float* __restrict__ Whh,
    const float* __restrict__ bih, const float* __restrict__ bhh,
    float* __restrict__ qf,
    const float* __restrict__ images, const float* __restrict__ c0W,
    const float* __restrict__ c0b, float* __restrict__ conv0o,
    float* __restrict__ stats,
    const float* __restrict__ gsW, unsigned short* __restrict__ Wbf)
{
    const int bx = blockIdx.x;
    if (bx < 32) {
        lstm_body(q, embW, Wih, Whh, bih, bhh, qf, bx);
    } else if (bx < 544) {
        conv_body<3, 16, false, 1024>(images, c0W, c0b, nullptr, nullptr, nullptr, 0.f,
                                      conv0o, stats, 128, 128, 64, 64, 4, bx - 32);
    } else {
        int i = ((bx - 544) << 10) + threadIdx.x;
#pragma unroll
        for (int u = 0; u < 4; u++) {
            Wbf[i] = f2bf(gsW[i]);
            i += 48 * 1024;
        }
    }
}

// ---------------- A,B,QT projections: 4 blocks per n, LDS-staged g0W ----------------
__global__ __launch_bounds__(256) void abqt_kernel(
    const float* __restrict__ feat,  // (32,24,8,8) raw conv3
    const float* __restrict__ stats, const float* __restrict__ g,
    const float* __restrict__ b, float invM,
    const float* __restrict__ qf,    // (32,128)
    const float* __restrict__ g0W,   // (256,180)
    const float* __restrict__ g0b,
    float* __restrict__ A, float* __restrict__ Bm, float* __restrict__ QT)
{
    const int n = blockIdx.x >> 2, iq = blockIdx.x & 3, k = threadIdx.x;
    __shared__ float wAB[256][53];   // g0W[:, 0:52] staged, padded
    __shared__ float wq[64][128];    // g0W[iq*64 + :, 52:180]
    __shared__ float obj[16][28];
    __shared__ float qs[RNN];
    __shared__ float sc[24], sh[24];
    if (k < 24) {
        float mu  = stats[2 * k] * invM;
        float var = stats[2 * k + 1] * invM - mu * mu;
        float rs  = rsqrtf(var + 1e-5f);
        sc[k] = rs * g[k];
        sh[k] = b[k] - mu * rs * g[k];
    }
    if (k >= 128) qs[k - 128] = qf[n * RNN + (k - 128)];
    for (int idx = k; idx < 256 * 52; idx += 256) {
        int kr = idx / 52, c = idx % 52;
        wAB[kr][c] = g0W[kr * GIN + c];
    }
    for (int idx = k; idx < 64 * 128; idx += 256) {
        int r = idx >> 7, d = idx & 127;
        wq[r][d] = g0W[(((iq << 6) + r)) * GIN + 52 + d];
    }
    __syncthreads();
    for (int idx = k; idx < 24 * 16; idx += 256) {
        int c = idx >> 4, il = idx & 15;
        int i = (iq << 4) + il;
        float v = feat[(n * CDIM + c) * 64 + i];
        obj[il][c] = fmaxf(v * sc[c] + sh[c], 0.f);
    }
    if (k < 16) {
        int i = (iq << 4) + k;
        obj[k][24] = (float)(i & 7)  * (1.f / 7.f);   // xc
        obj[k][25] = (float)(i >> 3) * (1.f / 7.f);   // yc
        obj[k][26] = 0.f; obj[k][27] = 0.f;
    }
    __syncthreads();
    if (k < 64) {
        int kr = (iq << 6) + k;
        float qv = g0b[kr];
#pragma unroll
        for (int d = 0; d < RNN; d++) qv += wq[k][d] * qs[d];
        QT[(n << 8) + kr] = qv;
    }
    float wA[26], wB[26];
#pragma unroll
    for (int c = 0; c < 26; c++) { wA[c] = wAB[k][c]; wB[c] = wAB[k][26 + c]; }
    for (int il = 0; il < 16; il++) {
        const f32x4* op = (const f32x4*)obj[il];
        f32x4 r0 = op[0], r1 = op[1], r2 = op[2], r3 = op[3],
              r4 = op[4], r5 = op[5], r6 = op[6];
        float a = 0.f, bb = 0.f;
#pragma unroll
        for (int p = 0; p < 4; p++) {
            a += wA[p] * r0[p] + wA[4 + p] * r1[p] + wA[8 + p] * r2[p]
               + wA[12 + p] * r3[p] + wA[16 + p] * r4[p] + wA[20 + p] * r5[p];
            bb += wB[p] * r0[p] + wB[4 + p] * r1[p] + wB[8 + p] * r2[p]
                + wB[12 + p] * r3[p] + wB[16 + p] * r4[p] + wB[20 + p] * r5[p];
        }
        a += wA[24] * r6[0] + wA[25] * r6[1];
        bb += wB[24] * r6[0] + wB[25] * r6[1];
        int i = (iq << 4) + il;
        A [(((n << 6) + i) << 8) + k] = a;
        Bm[(((n << 6) + i) << 8) + k] = bb;
    }
}

// ---------------- fused 3x(256->256) g-MLP + pair sum, bf16 MFMA ----------------
// ROW-partitioned: 256 thr = 4 waves; wave w owns rows w*32..+32, ALL 256 cols.
// LDS X reads 4x fewer (2/wave/kb); W frags identical across waves (L1 dedup);
// acc[16][2] f32x4 = 128 VGPR; launch_bounds(256,2) -> 256 cap, 2 blocks/CU.
__global__ __launch_bounds__(256, 2) void gs_fused(
    const float* __restrict__ A, const float* __restrict__ Bm, const float* __restrict__ QT,
    const unsigned short* __restrict__ Wb,   // (3,256,256) bf16
    const float* __restrict__ gsb,           // (3,256)
    float* __restrict__ partial)             // (1024,256)
{
    __shared__ __align__(16) unsigned short Xs[128 * 256];  // 64 KB
    __shared__ float AQ[2][256];
    __shared__ float biasv[3][256];
    __shared__ float red[4][256];
    const int raw = blockIdx.x;
    const int bb = (raw & 7) * 128 + (raw >> 3);   // XCD-contiguous: 4 n's per XCD
    const int n = bb >> 5, ip = bb & 31, tid = threadIdx.x;
    const int lane = tid & 63, w = tid >> 6, l15 = lane & 15, lh = lane >> 4;

    {
        float qt = QT[(n << 8) + tid];
        AQ[0][tid] = A[(((n << 6) + ip * 2)     << 8) + tid] + qt;
        AQ[1][tid] = A[(((n << 6) + ip * 2 + 1) << 8) + tid] + qt;
        biasv[0][tid] = gsb[tid];
        biasv[1][tid] = gsb[256 + tid];
        biasv[2][tid] = gsb[512 + tid];
    }
    __syncthreads();

    // build h0 = relu(A_i + B_j + QT) into Xs; 128 rows x 32 col-groups
#pragma unroll
    for (int it = 0; it < 16; it++) {
        int task = tid + (it << 8);
        int r = task >> 5, g = task & 31;
        int isub = r >> 6, j = r & 63;
        const f32x4* bp = (const f32x4*)(Bm + (((n << 6) + j) << 8) + (g << 3));
        f32x4 b0 = bp[0], b1 = bp[1];
        u16x8 pk;
        int c0 = g << 3;
#pragma unroll
        for (int p = 0; p < 4; p++) {
            pk[p]     = f2bf(fmaxf(b0[p] + AQ[isub][c0 + p], 0.f));
            pk[p + 4] = f2bf(fmaxf(b1[p] + AQ[isub][c0 + 4 + p], 0.f));
        }
        *(u16x8*)((char*)Xs + r * 512 + ((g ^ (r & 7)) << 4)) = pk;
    }

    f32x4 acc[16][2];                // [col-tile 0..15][row-slab 0..1]
    const f32x4 zero4 = {0.f, 0.f, 0.f, 0.f};
    for (int layer = 0; layer < 3; layer++) {
#pragma unroll
        for (int tc = 0; tc < 16; tc++) { acc[tc][0] = zero4; acc[tc][1] = zero4; }
        // W row = tc*16 + l15 (same for all waves), K offset lh*8 (+kb*32)
        const unsigned short* wbase = Wb + (layer << 16) + (l15 << 8) + (lh << 3);
        __syncthreads();   // Xs ready (build or previous writeback)
        bf16x8 xa[2], xn[2];
#pragma unroll
        for (int sl = 0; sl < 2; sl++) {
            int ar = (w << 5) + (sl << 4) + l15;
            int au = lh ^ (ar & 7);
            xa[sl] = *(const bf16x8*)((const char*)Xs + ar * 512 + (au << 4));
        }
#pragma unroll
        for (int kb = 0; kb < 8; kb++) {
            bf16x8 wa[16];
#pragma unroll
            for (int tc = 0; tc < 16; tc++)
                wa[tc] = *(const bf16x8*)(wbase + (tc << 12) + (kb << 5));
            if (kb < 7) {
#pragma unroll
                for (int sl = 0; sl < 2; sl++) {
                    int ar = (w << 5) + (sl << 4) + l15;
                    int au = (((kb + 1) << 2) + lh) ^ (ar & 7);
                    xn[sl] = *(const bf16x8*)((const char*)Xs + ar * 512 + (au << 4));
                }
            }
#pragma unroll
            for (int tc = 0; tc < 16; tc++) {
                acc[tc][0] = __builtin_amdgcn_mfma_f32_16x16x32_bf16(
                    wa[tc], xa[0], acc[tc][0], 0, 0, 0);
                acc[tc][1] = __builtin_amdgcn_mfma_f32_16x16x32_bf16(
                    wa[tc], xa[1], acc[tc][1], 0, 0, 0);
            }
            if (kb < 7) { xa[0] = xn[0]; xa[1] = xn[1]; }
        }
        if (layer < 2) {
            __syncthreads();  // all waves done reading Xs before overwrite
#pragma unroll
            for (int tc = 0; tc < 16; tc++) {
                int c0 = (tc << 4) + (lh << 2);
                f32x4 bv = *(const f32x4*)&biasv[layer][c0];
#pragma unroll
                for (int sl = 0; sl < 2; sl++) {
                    int row = (w << 5) + (sl << 4) + l15;
                    s16x4 pk;
                    pk[0] = (short)f2bf(fmaxf(acc[tc][sl][0] + bv[0], 0.f));
                    pk[1] = (short)f2bf(fmaxf(acc[tc][sl][1] + bv[1], 0.f));
                    pk[2] = (short)f2bf(fmaxf(acc[tc][sl][2] + bv[2], 0.f));
                    pk[3] = (short)f2bf(fmaxf(acc[tc][sl][3] + bv[3], 0.f));
                    *(s16x4*)((char*)Xs + row * 512 + (((c0 >> 3) ^ (row & 7)) << 4)
                              + ((c0 & 7) << 1)) = pk;
                }
            }
        } else {
            // final: relu + sum over this wave's 32 rows, shfl-reduce over l15
#pragma unroll
            for (int tc = 0; tc < 16; tc++) {
                int c0 = (tc << 4) + (lh << 2);
                f32x4 bv = *(const f32x4*)&biasv[2][c0];
                f32x4 v;
#pragma unroll
                for (int p = 0; p < 4; p++) {
                    float s = fmaxf(acc[tc][0][p] + bv[p], 0.f)
                            + fmaxf(acc[tc][1][p] + bv[p], 0.f);
                    s += __shfl_xor(s, 1, 64);
                    s += __shfl_xor(s, 2, 64);
                    s += __shfl_xor(s, 4, 64);
                    s += __shfl_xor(s, 8, 64);
                    v[p] = s;
                }
                if (l15 == 0) *(f32x4*)&red[w][c0] = v;
            }
            __syncthreads();
            partial[(size_t)bb * 256 + tid] =
                red[0][tid] + red[1][tid] + red[2][tid] + red[3][tid];
        }
    }
}

// ---------------- f-MLP: thread-per-row GEMV, vec4 + deep ILP ----------------
__device__ __forceinline__ float dot256(const float* __restrict__ wr,
                                        const float* __restrict__ x)
{
    const f32x4* w4 = (const f32x4*)wr;
    const f32x4* x4 = (const f32x4*)x;
    f32x4 a0 = {0.f, 0.f, 0.f, 0.f}, a1 = a0, a2 = a0, a3 = a0;
#pragma unroll 8
    for (int c = 0; c < 64; c += 4) {
        f32x4 w0 = w4[c], w1 = w4[c + 1], w2 = w4[c + 2], w3 = w4[c + 3];
        f32x4 x0 = x4[c], x1 = x4[c + 1], x2 = x4[c + 2], x3 = x4[c + 3];
        a0 += w0 * x0; a1 += w1 * x1; a2 += w2 * x2; a3 += w3 * x3;
    }
    f32x4 a = (a0 + a1) + (a2 + a3);
    return (a[0] + a[1]) + (a[2] + a[3]);
}

__global__ __launch_bounds__(256) void f_mlp(
    const float* __restrict__ partial,
    const float* __restrict__ f0W, const float* __restrict__ f0b,
    const float* __restrict__ f1W, const float* __restrict__ f1b,
    const float* __restrict__ f2W, const float* __restrict__ f2b,
    float* __restrict__ out)
{
    const int n = blockIdx.x, k = threadIdx.x;
    __shared__ float fin[256], h1[256], h2[256];
    const float* pb = partial + (size_t)(n * 32) * 256 + k;
    float s0 = 0.f, s1 = 0.f, s2 = 0.f, s3 = 0.f;
#pragma unroll
    for (int b = 0; b < 32; b += 4) {
        s0 += pb[(b + 0) << 8];
        s1 += pb[(b + 1) << 8];
        s2 += pb[(b + 2) << 8];
        s3 += pb[(b + 3) << 8];
    }
    fin[k] = (s0 + s1) + (s2 + s3);
    __syncthreads();
    h1[k] = fmaxf(dot256(f0W + (k << 8), fin) + f0b[k], 0.f);
    __syncthreads();
    h2[k] = fmaxf(dot256(f1W + (k << 8), h1) + f1b[k], 0.f);
    __syncthreads();
    if (k < 32)
        out[(n << 5) + k] = dot256(f2W + (k << 8), h2) + f2b[k];
}

extern "C" void kernel_launch(void* const* d_in, const int* in_sizes, int n_in,
                              void* d_out, int out_size, void* d_ws, size_t ws_size,
                              hipStream_t stream)
{
    const int*   questions = (const int*)  d_in[0];
    const float* images = (const float*)d_in[1];
    const float* embW   = (const float*)d_in[2];
    const float* Wih    = (const float*)d_in[3];
    const float* Whh    = (const float*)d_in[4];
    const float* bih    = (const float*)d_in[5];
    const float* bhh    = (const float*)d_in[6];
    const float* c0W    = (const float*)d_in[7];
    const float* c0b    = (const float*)d_in[8];
    const float* bn0g   = (const float*)d_in[9];
    const float* bn0b   = (const float*)d_in[10];
    const float* csW    = (const float*)d_in[11];
    const float* csb    = (const float*)d_in[12];
    const float* bnsg   = (const float*)d_in[13];
    const float* bnsb   = (const float*)d_in[14];
    const float* g0W    = (const float*)d_in[15];
    const float* g0b    = (const float*)d_in[16];
    const float* gsW    = (const float*)d_in[17];
    const float* gsb    = (const float*)d_in[18];
    const float* f0W    = (const float*)d_in[19];
    const float* f0b    = (const float*)d_in[20];
    const float* f1W    = (const float*)d_in[21];
    const float* f1b    = (const float*)d_in[22];
    const float* f2W    = (const float*)d_in[23];
    const float* f2b    = (const float*)d_in[24];

    float* ws  = (float*)d_ws;
    float* out = (float*)d_out;

    // workspace layout (floats)
    float* conv0o = ws;                 // 3,145,728  (32,24,64,64)
    float* conv1o = ws + 3145728;       //   786,432  (32,24,32,32)
    float* conv2o = ws + 3932160;       //   196,608  (32,24,16,16)
    float* conv3o = ws + 4128768;       //    49,152  (32,24,8,8)
    float* stats  = ws + 4177920;       //       192
    float* qf     = ws + 4178112;       //     4,096  (32,128)
    unsigned short* Wbf = (unsigned short*)(ws + 4182208);  // 196,608 bf16
    // overlay into conv0o region (dead after conv1 consumes it):
    float* Abuf   = ws;                 //   524,288  (32,64,256)
    float* Bbuf   = ws + 524288;        //   524,288
    float* QTb    = ws + 1048576;       //     8,192  (32,256)
    float* part   = ws + 1155072;       //   262,144  (1024,256)

    hipMemsetAsync(stats, 0, 192 * sizeof(float), stream);

    // lstm (32 blocks) + conv0 (512) + gsW->bf16 cvt (48)
    fused_front<<<592, 1024, 0, stream>>>(questions, embW, Wih, Whh, bih, bhh, qf,
                                          images, c0W, c0b, conv0o, stats, gsW, Wbf);
    // conv1: BN0 applied on load; out (32,24,32,32)
    conv_tiled<24, 8, true><<<512, 256, 0, stream>>>(
        conv0o, csW, csb, stats, bn0g, bn0b, 1.f / 131072.f,
        conv1o, stats + 48, 64, 64, 32, 32, 4);
    // conv2: out (32,24,16,16)
    conv_tiled<24, 8, true><<<128, 256, 0, stream>>>(
        conv1o, csW + 5184, csb + 24, stats + 48, bnsg, bnsb, 1.f / 32768.f,
        conv2o, stats + 96, 32, 32, 16, 16, 2);
    // conv3: out (32,24,8,8)
    conv_tiled<24, 8, true><<<32, 256, 0, stream>>>(
        conv2o, csW + 10368, csb + 48, stats + 96, bnsg + 24, bnsb + 24, 1.f / 8192.f,
        conv3o, stats + 144, 16, 16, 8, 8, 1);

    abqt_kernel<<<128, 256, 0, stream>>>(conv3o, stats + 144, bnsg + 48, bnsb + 48,
                                         1.f / 2048.f, qf, g0W, g0b, Abuf, Bbuf, QTb);
    gs_fused<<<1024, 256, 0, stream>>>(Abuf, Bbuf, QTb, Wbf, gsb, part);
    f_mlp<<<32, 256, 0, stream>>>(part, f0W, f0b, f1W, f1b, f2W, f2b, out);
}

// Round 9
// 327.333 us; speedup vs baseline: 1.3653x; 1.3653x over previous
//
#include <hip/hip_runtime.h>

// ---------- model dims ----------
#define NB   32
#define TT   46
#define RNN  128
#define CDIM 24
#define GD   256
#define GIN  180

typedef __attribute__((ext_vector_type(8))) short  bf16x8;
typedef __attribute__((ext_vector_type(4))) short  s16x4;
typedef __attribute__((ext_vector_type(8))) unsigned short u16x8;
typedef __attribute__((ext_vector_type(4))) float  f32x4;

__device__ __forceinline__ unsigned short f2bf(float v) {
    unsigned u = __float_as_uint(v);
    u = u + 0x7fffu + ((u >> 16) & 1u);   // RNE
    return (unsigned short)(u >> 16);
}

// ---------------- LSTM body (512 threads, one block per n) ----------------
// weights register-resident (f32x4), hs/xs read as uniform-broadcast b128
__device__ __forceinline__ void lstm_body(
    const int* __restrict__ q, const float* __restrict__ embW,
    const float* __restrict__ Wih, const float* __restrict__ Whh,
    const float* __restrict__ bih, const float* __restrict__ bhh,
    float* __restrict__ qf, int n)
{
    const int tid = threadIdx.x;
    __shared__ __align__(16) float xs[32], hs[RNN];
    __shared__ float zg[512];
    f32x4 wih[8], whh[32];
    {
        const f32x4* wp = (const f32x4*)(Wih + tid * 32);
#pragma unroll
        for (int j = 0; j < 8; j++) wih[j] = wp[j];
        const f32x4* hp = (const f32x4*)(Whh + tid * RNN);
#pragma unroll
        for (int j = 0; j < 32; j++) whh[j] = hp[j];
    }
    const float bias = bih[tid] + bhh[tid];
    float creg = 0.f;
    if (tid < RNN) hs[tid] = 0.f;
    float xr = (tid < 32) ? embW[q[n * TT] * 32 + tid] : 0.f;
    __syncthreads();
    for (int t = 0; t < TT; t++) {
        if (tid < 32) xs[tid] = xr;
        __syncthreads();           // xs ready, hs ready
        if (tid < 32 && t + 1 < TT) xr = embW[q[n * TT + t + 1] * 32 + tid];  // prefetch
        const f32x4* h4 = (const f32x4*)hs;
        const f32x4* x4 = (const f32x4*)xs;
        f32x4 a0 = {0.f, 0.f, 0.f, 0.f}, a1 = a0, a2 = a0, a3 = a0;
#pragma unroll
        for (int j = 0; j < 8; j += 4) {
            a0 += wih[j] * x4[j];     a1 += wih[j + 1] * x4[j + 1];
            a2 += wih[j + 2] * x4[j + 2]; a3 += wih[j + 3] * x4[j + 3];
        }
#pragma unroll
        for (int j = 0; j < 32; j += 4) {
            a0 += whh[j] * h4[j];     a1 += whh[j + 1] * h4[j + 1];
            a2 += whh[j + 2] * h4[j + 2]; a3 += whh[j + 3] * h4[j + 3];
        }
        f32x4 a = (a0 + a1) + (a2 + a3);
        zg[tid] = bias + ((a[0] + a[1]) + (a[2] + a[3]));
        __syncthreads();
        if (tid < RNN) {
            float ig = 1.f / (1.f + __expf(-zg[tid]));
            float fg = 1.f / (1.f + __expf(-zg[RNN + tid]));
            float gg = tanhf(zg[2 * RNN + tid]);
            float og = 1.f / (1.f + __expf(-zg[3 * RNN + tid]));
            float cn = fg * creg + ig * gg;
            creg = cn;
            hs[tid] = og * tanhf(cn);
        }
        __syncthreads();
    }
    if (tid < RNN) qf[n * RNN + tid] = hs[tid];
}

// ---------------- tiled conv 3x3 s2 p1 body ----------------
template<int CIN, int TILE, bool BNIN, int BS>
__device__ __forceinline__ void conv_body(
    const float* __restrict__ in, const float* __restrict__ Wg,
    const float* __restrict__ bias,
    const float* __restrict__ pstats, const float* __restrict__ pg,
    const float* __restrict__ pb, float pinvM,
    float* __restrict__ out, float* __restrict__ stats,
    int HIN, int WIN, int HO, int WO, int tilesX, int bx)
{
    constexpr int NPIX = TILE * TILE;
    constexpr int CPG  = BS / NPIX;
    constexpr int COPT = 24 / CPG;
    constexpr int WPB  = BS / 64;
    constexpr int WPC  = NPIX / 64;
    constexpr int S  = 2 * TILE + 1;
    constexpr int SP = S + 1;
    __shared__ float in_t[CIN][S][SP];
    __shared__ float r1s[WPB][COPT], r2s[WPB][COPT];
    __shared__ float sc[CIN], sh[CIN];
    const int tid = threadIdx.x;
    const int tx = bx % tilesX;
    const int ty = (bx / tilesX) % tilesX;
    const int n  = bx / (tilesX * tilesX);

    if (BNIN) {
        if (tid < CIN) {
            float mu  = pstats[2 * tid] * pinvM;
            float var = pstats[2 * tid + 1] * pinvM - mu * mu;
            float rs  = rsqrtf(var + 1e-5f);
            sc[tid] = rs * pg[tid];
            sh[tid] = pb[tid] - mu * rs * pg[tid];
        }
        __syncthreads();
    }
    const int iy0 = ty * 2 * TILE - 1, ix0 = tx * 2 * TILE - 1;
    for (int idx = tid; idx < CIN * S * S; idx += BS) {
        int ci = idx / (S * S), r = idx % (S * S);
        int ry = r / S, rx = r % S;
        int gy = iy0 + ry, gx = ix0 + rx;
        float v = 0.f;
        if ((unsigned)gy < (unsigned)HIN && (unsigned)gx < (unsigned)WIN) {
            v = in[((size_t)(n * CIN + ci) * HIN + gy) * WIN + gx];
            if (BNIN) v = fmaxf(v * sc[ci] + sh[ci], 0.f);
        }
        in_t[ci][ry][rx] = v;
    }
    __syncthreads();

    const int p   = tid % NPIX;
    const int co0 = __builtin_amdgcn_readfirstlane((tid / NPIX) * COPT);
    const int ly  = (p / TILE) * 2, lx = (p % TILE) * 2;
    float acc[COPT];
#pragma unroll
    for (int c = 0; c < COPT; c++) acc[c] = bias[co0 + c];
    for (int ci = 0; ci < CIN; ci++) {
#pragma unroll
        for (int ky = 0; ky < 3; ky++) {
            const float* row = &in_t[ci][ly + ky][lx];
#pragma unroll
            for (int kx = 0; kx < 3; kx++) {
                float v = row[kx];
#pragma unroll
                for (int c = 0; c < COPT; c++)
                    acc[c] += v * Wg[(((co0 + c) * CIN + ci) * 3 + ky) * 3 + kx];
            }
        }
    }
    const int oy = ty * TILE + p / TILE, ox = tx * TILE + p % TILE;
#pragma unroll
    for (int c = 0; c < COPT; c++)
        out[((size_t)(n * 24 + co0 + c) * HO + oy) * WO + ox] = acc[c];

    const int lane = tid & 63, wv = tid >> 6;
#pragma unroll
    for (int c = 0; c < COPT; c++) {
        float s1 = acc[c], s2 = acc[c] * acc[c];
#pragma unroll
        for (int off = 1; off < 64; off <<= 1) {
            s1 += __shfl_xor(s1, off, 64);
            s2 += __shfl_xor(s2, off, 64);
        }
        if (lane == 0) { r1s[wv][c] = s1; r2s[wv][c] = s2; }
    }
    __syncthreads();
    if (tid < 24) {
        int cg = tid / COPT, slot = tid % COPT;
        float t1 = 0.f, t2 = 0.f;
#pragma unroll
        for (int u = 0; u < WPC; u++) { t1 += r1s[cg * WPC + u][slot]; t2 += r2s[cg * WPC + u][slot]; }
        atomicAdd(&stats[tid * 2],     t1);
        atomicAdd(&stats[tid * 2 + 1], t2);
    }
}

template<int CIN, int TILE, bool BNIN>
__global__ __launch_bounds__(256) void conv_tiled(
    const float* __restrict__ in, const float* __restrict__ Wg,
    const float* __restrict__ bias,
    const float* __restrict__ pstats, const float* __restrict__ pg,
    const float* __restrict__ pb, float pinvM,
    float* __restrict__ out, float* __restrict__ stats,
    int HIN, int WIN, int HO, int WO, int tilesX)
{
    conv_body<CIN, TILE, BNIN, 256>(in, Wg, bias, pstats, pg, pb, pinvM,
                                    out, stats, HIN, WIN, HO, WO, tilesX, blockIdx.x);
}

// ---------------- merged front: lstm (0-31) + conv0 (32-543) + cvt (544-639) ----------------
__global__ __launch_bounds__(512, 2) void fused_front(
    const int* __restrict__ q, const float* __restrict__ embW,
    const float* __restrict__ Wih, const float* __restrict__ Whh,
    const float* __restrict__ bih, const float* __restrict__ bhh,
    float* __restrict__ qf,
    const float* __restrict__ images, const float* __restrict__ c0W,
    const float* __restrict__ c0b, float* __restrict__ conv0o,
    float* __restrict__ stats,
    const float* __restrict__ gsW, unsigned short* __restrict__ Wbf)
{
    const int bx = blockIdx.x;
    if (bx < 32) {
        lstm_body(q, embW, Wih, Whh, bih, bhh, qf, bx);
    } else if (bx < 544) {
        conv_body<3, 16, false, 512>(images, c0W, c0b, nullptr, nullptr, nullptr, 0.f,
                                     conv0o, stats, 128, 128, 64, 64, 4, bx - 32);
    } else {
        int i = ((bx - 544) << 9) + threadIdx.x;
#pragma unroll
        for (int u = 0; u < 4; u++) {
            Wbf[i] = f2bf(gsW[i]);
            i += 96 * 512;
        }
    }
}

// ---------------- A,B,QT projections: 4 blocks per n, LDS-staged g0W ----------------
__global__ __launch_bounds__(256) void abqt_kernel(
    const float* __restrict__ feat,  // (32,24,8,8) raw conv3
    const float* __restrict__ stats, const float* __restrict__ g,
    const float* __restrict__ b, float invM,
    const float* __restrict__ qf,    // (32,128)
    const float* __restrict__ g0W,   // (256,180)
    const float* __restrict__ g0b,
    float* __restrict__ A, float* __restrict__ Bm, float* __restrict__ QT)
{
    const int n = blockIdx.x >> 2, iq = blockIdx.x & 3, k = threadIdx.x;
    __shared__ float wAB[256][53];   // g0W[:, 0:52] staged, padded
    __shared__ float wq[64][128];    // g0W[iq*64 + :, 52:180]
    __shared__ float obj[16][28];
    __shared__ float qs[RNN];
    __shared__ float sc[24], sh[24];
    if (k < 24) {
        float mu  = stats[2 * k] * invM;
        float var = stats[2 * k + 1] * invM - mu * mu;
        float rs  = rsqrtf(var + 1e-5f);
        sc[k] = rs * g[k];
        sh[k] = b[k] - mu * rs * g[k];
    }
    if (k >= 128) qs[k - 128] = qf[n * RNN + (k - 128)];
    for (int idx = k; idx < 256 * 52; idx += 256) {
        int kr = idx / 52, c = idx % 52;
        wAB[kr][c] = g0W[kr * GIN + c];
    }
    for (int idx = k; idx < 64 * 128; idx += 256) {
        int r = idx >> 7, d = idx & 127;
        wq[r][d] = g0W[(((iq << 6) + r)) * GIN + 52 + d];
    }
    __syncthreads();
    for (int idx = k; idx < 24 * 16; idx += 256) {
        int c = idx >> 4, il = idx & 15;
        int i = (iq << 4) + il;
        float v = feat[(n * CDIM + c) * 64 + i];
        obj[il][c] = fmaxf(v * sc[c] + sh[c], 0.f);
    }
    if (k < 16) {
        int i = (iq << 4) + k;
        obj[k][24] = (float)(i & 7)  * (1.f / 7.f);   // xc
        obj[k][25] = (float)(i >> 3) * (1.f / 7.f);   // yc
        obj[k][26] = 0.f; obj[k][27] = 0.f;
    }
    __syncthreads();
    if (k < 64) {
        int kr = (iq << 6) + k;
        float qv = g0b[kr];
#pragma unroll
        for (int d = 0; d < RNN; d++) qv += wq[k][d] * qs[d];
        QT[(n << 8) + kr] = qv;
    }
    float wA[26], wB[26];
#pragma unroll
    for (int c = 0; c < 26; c++) { wA[c] = wAB[k][c]; wB[c] = wAB[k][26 + c]; }
    for (int il = 0; il < 16; il++) {
        const f32x4* op = (const f32x4*)obj[il];
        f32x4 r0 = op[0], r1 = op[1], r2 = op[2], r3 = op[3],
              r4 = op[4], r5 = op[5], r6 = op[6];
        float a = 0.f, bb = 0.f;
#pragma unroll
        for (int p = 0; p < 4; p++) {
            a += wA[p] * r0[p] + wA[4 + p] * r1[p] + wA[8 + p] * r2[p]
               + wA[12 + p] * r3[p] + wA[16 + p] * r4[p] + wA[20 + p] * r5[p];
            bb += wB[p] * r0[p] + wB[4 + p] * r1[p] + wB[8 + p] * r2[p]
                + wB[12 + p] * r3[p] + wB[16 + p] * r4[p] + wB[20 + p] * r5[p];
        }
        a += wA[24] * r6[0] + wA[25] * r6[1];
        bb += wB[24] * r6[0] + wB[25] * r6[1];
        int i = (iq << 4) + il;
        A [(((n << 6) + i) << 8) + k] = a;
        Bm[(((n << 6) + i) << 8) + k] = bb;
    }
}

// ---------------- fused 3x(256->256) g-MLP + pair sum, bf16 MFMA ----------------
// 256 thr = 4 waves in a 2x2 (row-half x col-half) grid: each wave owns
// 64 rows x 128 cols -> X LDS reads halved vs col-quarters (4 slabs/wave/kb);
// W global->reg + X LDS->reg register-prefetched one kb ahead (round-7 pipeline);
// XCD-swizzled blockIdx; 2 blocks/CU
__global__ __launch_bounds__(256, 2) void gs_fused(
    const float* __restrict__ A, const float* __restrict__ Bm, const float* __restrict__ QT,
    const unsigned short* __restrict__ Wb,   // (3,256,256) bf16
    const float* __restrict__ gsb,           // (3,256)
    float* __restrict__ partial)             // (1024,256)
{
    __shared__ __align__(16) unsigned short Xs[128 * 256];  // 64 KB
    __shared__ float AQ[2][256];
    __shared__ float biasv[3][256];
    __shared__ float red[2][256];
    const int raw = blockIdx.x;
    const int bb = (raw & 7) * 128 + (raw >> 3);   // XCD-contiguous: 4 n's per XCD
    const int n = bb >> 5, ip = bb & 31, tid = threadIdx.x;
    const int lane = tid & 63, w = tid >> 6, l15 = lane & 15, lh = lane >> 4;
    const int rh = w >> 1, ch = w & 1;

    {
        float qt = QT[(n << 8) + tid];
        AQ[0][tid] = A[(((n << 6) + ip * 2)     << 8) + tid] + qt;
        AQ[1][tid] = A[(((n << 6) + ip * 2 + 1) << 8) + tid] + qt;
        biasv[0][tid] = gsb[tid];
        biasv[1][tid] = gsb[256 + tid];
        biasv[2][tid] = gsb[512 + tid];
    }
    __syncthreads();

    // build h0 = relu(A_i + B_j + QT) into Xs; 128 rows x 32 col-groups
#pragma unroll
    for (int it = 0; it < 16; it++) {
        int task = tid + (it << 8);
        int r = task >> 5, g = task & 31;
        int isub = r >> 6, j = r & 63;
        const f32x4* bp = (const f32x4*)(Bm + (((n << 6) + j) << 8) + (g << 3));
        f32x4 b0 = bp[0], b1 = bp[1];
        u16x8 pk;
        int c0 = g << 3;
#pragma unroll
        for (int p = 0; p < 4; p++) {
            pk[p]     = f2bf(fmaxf(b0[p] + AQ[isub][c0 + p], 0.f));
            pk[p + 4] = f2bf(fmaxf(b1[p] + AQ[isub][c0 + 4 + p], 0.f));
        }
        *(u16x8*)((char*)Xs + r * 512 + ((g ^ (r & 7)) << 4)) = pk;
    }

    f32x4 acc[8][4];                 // [col-tile 0..7][row-slab 0..3]
    const f32x4 zero4 = {0.f, 0.f, 0.f, 0.f};
    bf16x8 wa[8], wn[8], xa[4], xn[4];
    for (int layer = 0; layer < 3; layer++) {
#pragma unroll
        for (int tc = 0; tc < 8; tc++)
#pragma unroll
            for (int sl = 0; sl < 4; sl++) acc[tc][sl] = zero4;
        // per-lane W base: row = ch*128 + tc*16 + l15, K offset lh*8 (+kb*32)
        const unsigned short* wbase = Wb + (layer << 16)
                                    + (((ch << 7) + l15) << 8) + (lh << 3);
        // prefetch W for kb=0 BEFORE the barrier (independent of Xs)
#pragma unroll
        for (int tc = 0; tc < 8; tc++) wa[tc] = *(const bf16x8*)(wbase + (tc << 12));
        __syncthreads();   // Xs ready (build or previous writeback)
        // prefetch X for kb=0 (this wave's 64 rows)
#pragma unroll
        for (int sl = 0; sl < 4; sl++) {
            int ar = (rh << 6) + (sl << 4) + l15;
            int au = lh ^ (ar & 7);
            xa[sl] = *(const bf16x8*)((const char*)Xs + ar * 512 + (au << 4));
        }
#pragma unroll
        for (int kb = 0; kb < 8; kb++) {
            if (kb < 7) {
#pragma unroll
                for (int tc = 0; tc < 8; tc++)
                    wn[tc] = *(const bf16x8*)(wbase + (tc << 12) + ((kb + 1) << 5));
#pragma unroll
                for (int sl = 0; sl < 4; sl++) {
                    int ar = (rh << 6) + (sl << 4) + l15;
                    int au = (((kb + 1) << 2) + lh) ^ (ar & 7);
                    xn[sl] = *(const bf16x8*)((const char*)Xs + ar * 512 + (au << 4));
                }
            }
#pragma unroll
            for (int tc = 0; tc < 8; tc++)
#pragma unroll
                for (int sl = 0; sl < 4; sl++)
                    acc[tc][sl] = __builtin_amdgcn_mfma_f32_16x16x32_bf16(
                        wa[tc], xa[sl], acc[tc][sl], 0, 0, 0);
            if (kb < 7) {
#pragma unroll
                for (int tc = 0; tc < 8; tc++) wa[tc] = wn[tc];
#pragma unroll
                for (int sl = 0; sl < 4; sl++) xa[sl] = xn[sl];
            }
        }
        if (layer < 2) {
            __syncthreads();  // all waves done reading Xs before overwrite
#pragma unroll
            for (int tc = 0; tc < 8; tc++) {
                int c0 = (ch << 7) + (tc << 4) + (lh << 2);
                f32x4 bv = *(const f32x4*)&biasv[layer][c0];
#pragma unroll
                for (int sl = 0; sl < 4; sl++) {
                    int row = (rh << 6) + (sl << 4) + l15;
                    s16x4 pk;
                    pk[0] = (short)f2bf(fmaxf(acc[tc][sl][0] + bv[0], 0.f));
                    pk[1] = (short)f2bf(fmaxf(acc[tc][sl][1] + bv[1], 0.f));
                    pk[2] = (short)f2bf(fmaxf(acc[tc][sl][2] + bv[2], 0.f));
                    pk[3] = (short)f2bf(fmaxf(acc[tc][sl][3] + bv[3], 0.f));
                    *(s16x4*)((char*)Xs + row * 512 + (((c0 >> 3) ^ (row & 7)) << 4)
                              + ((c0 & 7) << 1)) = pk;
                }
            }
        } else {
            // final: relu + sum over this wave's 64 rows -> red[rh], then combine
#pragma unroll
            for (int tc = 0; tc < 8; tc++) {
                int c0 = (ch << 7) + (tc << 4) + (lh << 2);
                f32x4 bv = *(const f32x4*)&biasv[2][c0];
                f32x4 cs;
#pragma unroll
                for (int p = 0; p < 4; p++) {
                    float s = 0.f;
#pragma unroll
                    for (int sl = 0; sl < 4; sl++) s += fmaxf(acc[tc][sl][p] + bv[p], 0.f);
                    s += __shfl_xor(s, 1, 64);
                    s += __shfl_xor(s, 2, 64);
                    s += __shfl_xor(s, 4, 64);
                    s += __shfl_xor(s, 8, 64);
                    cs[p] = s;
                }
                if (l15 == 0) *(f32x4*)&red[rh][c0] = cs;
            }
            __syncthreads();
            partial[(size_t)bb * 256 + tid] = red[0][tid] + red[1][tid];
        }
    }
}

// ---------------- f-MLP: thread-per-row GEMV, vec4 + deep ILP ----------------
__device__ __forceinline__ float dot256(const float* __restrict__ wr,
                                        const float* __restrict__ x)
{
    const f32x4* w4 = (const f32x4*)wr;
    const f32x4* x4 = (const f32x4*)x;
    f32x4 a0 = {0.f, 0.f, 0.f, 0.f}, a1 = a0, a2 = a0, a3 = a0;
#pragma unroll 8
    for (int c = 0; c < 64; c += 4) {
        f32x4 w0 = w4[c], w1 = w4[c + 1], w2 = w4[c + 2], w3 = w4[c + 3];
        f32x4 x0 = x4[c], x1 = x4[c + 1], x2 = x4[c + 2], x3 = x4[c + 3];
        a0 += w0 * x0; a1 += w1 * x1; a2 += w2 * x2; a3 += w3 * x3;
    }
    f32x4 a = (a0 + a1) + (a2 + a3);
    return (a[0] + a[1]) + (a[2] + a[3]);
}

__global__ __launch_bounds__(256) void f_mlp(
    const float* __restrict__ partial,
    const float* __restrict__ f0W, const float* __restrict__ f0b,
    const float* __restrict__ f1W, const float* __restrict__ f1b,
    const float* __restrict__ f2W, const float* __restrict__ f2b,
    float* __restrict__ out)
{
    const int n = blockIdx.x, k = threadIdx.x;
    __shared__ float fin[256], h1[256], h2[256];
    const float* pb = partial + (size_t)(n * 32) * 256 + k;
    float s0 = 0.f, s1 = 0.f, s2 = 0.f, s3 = 0.f;
#pragma unroll
    for (int b = 0; b < 32; b += 4) {
        s0 += pb[(b + 0) << 8];
        s1 += pb[(b + 1) << 8];
        s2 += pb[(b + 2) << 8];
        s3 += pb[(b + 3) << 8];
    }
    fin[k] = (s0 + s1) + (s2 + s3);
    __syncthreads();
    h1[k] = fmaxf(dot256(f0W + (k << 8), fin) + f0b[k], 0.f);
    __syncthreads();
    h2[k] = fmaxf(dot256(f1W + (k << 8), h1) + f1b[k], 0.f);
    __syncthreads();
    if (k < 32)
        out[(n << 5) + k] = dot256(f2W + (k << 8), h2) + f2b[k];
}

extern "C" void kernel_launch(void* const* d_in, const int* in_sizes, int n_in,
                              void* d_out, int out_size, void* d_ws, size_t ws_size,
                              hipStream_t stream)
{
    const int*   questions = (const int*)  d_in[0];
    const float* images = (const float*)d_in[1];
    const float* embW   = (const float*)d_in[2];
    const float* Wih    = (const float*)d_in[3];
    const float* Whh    = (const float*)d_in[4];
    const float* bih    = (const float*)d_in[5];
    const float* bhh    = (const float*)d_in[6];
    const float* c0W    = (const float*)d_in[7];
    const float* c0b    = (const float*)d_in[8];
    const float* bn0g   = (const float*)d_in[9];
    const float* bn0b   = (const float*)d_in[10];
    const float* csW    = (const float*)d_in[11];
    const float* csb    = (const float*)d_in[12];
    const float* bnsg   = (const float*)d_in[13];
    const float* bnsb   = (const float*)d_in[14];
    const float* g0W    = (const float*)d_in[15];
    const float* g0b    = (const float*)d_in[16];
    const float* gsW    = (const float*)d_in[17];
    const float* gsb    = (const float*)d_in[18];
    const float* f0W    = (const float*)d_in[19];
    const float* f0b    = (const float*)d_in[20];
    const float* f1W    = (const float*)d_in[21];
    const float* f1b    = (const float*)d_in[22];
    const float* f2W    = (const float*)d_in[23];
    const float* f2b    = (const float*)d_in[24];

    float* ws  = (float*)d_ws;
    float* out = (float*)d_out;

    // workspace layout (floats)
    float* conv0o = ws;                 // 3,145,728  (32,24,64,64)
    float* conv1o = ws + 3145728;       //   786,432  (32,24,32,32)
    float* conv2o = ws + 3932160;       //   196,608  (32,24,16,16)
    float* conv3o = ws + 4128768;       //    49,152  (32,24,8,8)
    float* stats  = ws + 4177920;       //       192
    float* qf     = ws + 4178112;       //     4,096  (32,128)
    unsigned short* Wbf = (unsigned short*)(ws + 4182208);  // 196,608 bf16
    // overlay into conv0o region (dead after conv1 consumes it):
    float* Abuf   = ws;                 //   524,288  (32,64,256)
    float* Bbuf   = ws + 524288;        //   524,288
    float* QTb    = ws + 1048576;       //     8,192  (32,256)
    float* part   = ws + 1155072;       //   262,144  (1024,256)

    hipMemsetAsync(stats, 0, 192 * sizeof(float), stream);

    // lstm (32 blocks) + conv0 (512) + gsW->bf16 cvt (96)
    fused_front<<<640, 512, 0, stream>>>(questions, embW, Wih, Whh, bih, bhh, qf,
                                         images, c0W, c0b, conv0o, stats, gsW, Wbf);
    // conv1: BN0 applied on load; out (32,24,32,32)
    conv_tiled<24, 8, true><<<512, 256, 0, stream>>>(
        conv0o, csW, csb, stats, bn0g, bn0b, 1.f / 131072.f,
        conv1o, stats + 48, 64, 64, 32, 32, 4);
    // conv2: out (32,24,16,16)
    conv_tiled<24, 8, true><<<128, 256, 0, stream>>>(
        conv1o, csW + 5184, csb + 24, stats + 48, bnsg, bnsb, 1.f / 32768.f,
        conv2o, stats + 96, 32, 32, 16, 16, 2);
    // conv3: out (32,24,8,8)
    conv_tiled<24, 8, true><<<32, 256, 0, stream>>>(
        conv2o, csW + 10368, csb + 48, stats + 96, bnsg + 24, bnsb + 24, 1.f / 8192.f,
        conv3o, stats + 144, 16, 16, 8, 8, 1);

    abqt_kernel<<<128, 256, 0, stream>>>(conv3o, stats + 144, bnsg + 48, bnsb + 48,
                                         1.f / 2048.f, qf, g0W, g0b, Abuf, Bbuf, QTb);
    gs_fused<<<1024, 256, 0, stream>>>(Abuf, Bbuf, QTb, Wbf, gsb, part);
    f_mlp<<<32, 256, 0, stream>>>(part, f0W, f0b, f1W, f1b, f2W, f2b, out);
}

// Round 10
// 298.998 us; speedup vs baseline: 1.4947x; 1.0948x over previous
//
#include <hip/hip_runtime.h>

// ---------- model dims ----------
#define NB   32
#define TT   46
#define RNN  128
#define CDIM 24
#define GD   256
#define GIN  180

typedef __attribute__((ext_vector_type(8))) short  bf16x8;
typedef __attribute__((ext_vector_type(4))) short  s16x4;
typedef __attribute__((ext_vector_type(8))) unsigned short u16x8;
typedef __attribute__((ext_vector_type(4))) float  f32x4;

__device__ __forceinline__ unsigned short f2bf(float v) {
    unsigned u = __float_as_uint(v);
    u = u + 0x7fffu + ((u >> 16) & 1u);   // RNE
    return (unsigned short)(u >> 16);
}

// ---------------- LSTM body (1024 threads: 2 threads per gate, k-split) ----------------
// per-thread weights: 16+64 floats = 80 VGPR -> no spill at 128 cap
__device__ __forceinline__ void lstm_body(
    const int* __restrict__ q, const float* __restrict__ embW,
    const float* __restrict__ Wih, const float* __restrict__ Whh,
    const float* __restrict__ bih, const float* __restrict__ bhh,
    float* __restrict__ qf, int n)
{
    const int tid = threadIdx.x;          // 0..1023
    const int g = tid >> 1, h = tid & 1;  // gate, k-half
    __shared__ __align__(16) float xs[32], hs[RNN];
    __shared__ float zg[512];
    f32x4 wih[4], whh[16];
    {
        const f32x4* wp = (const f32x4*)(Wih + g * 32 + h * 16);
#pragma unroll
        for (int j = 0; j < 4; j++) wih[j] = wp[j];
        const f32x4* hp = (const f32x4*)(Whh + g * RNN + h * 64);
#pragma unroll
        for (int j = 0; j < 16; j++) whh[j] = hp[j];
    }
    const float bias = bih[g] + bhh[g];
    float creg = 0.f;
    if (tid < RNN) hs[tid] = 0.f;
    float xr = (tid < 32) ? embW[q[n * TT] * 32 + tid] : 0.f;
    __syncthreads();
    for (int t = 0; t < TT; t++) {
        if (tid < 32) xs[tid] = xr;
        __syncthreads();           // xs ready, hs ready
        if (tid < 32 && t + 1 < TT) xr = embW[q[n * TT + t + 1] * 32 + tid];
        const f32x4* x4 = (const f32x4*)xs + (h << 2);   // h*16 floats
        const f32x4* h4 = (const f32x4*)hs + (h << 4);   // h*64 floats
        f32x4 a0 = {0.f, 0.f, 0.f, 0.f}, a1 = a0, a2 = a0, a3 = a0;
        a0 += wih[0] * x4[0]; a1 += wih[1] * x4[1];
        a2 += wih[2] * x4[2]; a3 += wih[3] * x4[3];
#pragma unroll
        for (int j = 0; j < 16; j += 4) {
            a0 += whh[j] * h4[j];         a1 += whh[j + 1] * h4[j + 1];
            a2 += whh[j + 2] * h4[j + 2]; a3 += whh[j + 3] * h4[j + 3];
        }
        f32x4 a = (a0 + a1) + (a2 + a3);
        float p = (a[0] + a[1]) + (a[2] + a[3]);
        p += __shfl_xor(p, 1, 64);        // combine the two k-halves
        if (h == 0) zg[g] = p + bias;
        __syncthreads();
        if (tid < RNN) {
            float ig = 1.f / (1.f + __expf(-zg[tid]));
            float fg = 1.f / (1.f + __expf(-zg[RNN + tid]));
            float gg = tanhf(zg[2 * RNN + tid]);
            float og = 1.f / (1.f + __expf(-zg[3 * RNN + tid]));
            float cn = fg * creg + ig * gg;
            creg = cn;
            hs[tid] = og * tanhf(cn);
        }
        __syncthreads();
    }
    if (tid < RNN) qf[n * RNN + tid] = hs[tid];
}

// ---------------- tiled conv 3x3 s2 p1 body ----------------
template<int CIN, int TILE, bool BNIN, int BS>
__device__ __forceinline__ void conv_body(
    const float* __restrict__ in, const float* __restrict__ Wg,
    const float* __restrict__ bias,
    const float* __restrict__ pstats, const float* __restrict__ pg,
    const float* __restrict__ pb, float pinvM,
    float* __restrict__ out, float* __restrict__ stats,
    int HIN, int WIN, int HO, int WO, int tilesX, int bx)
{
    constexpr int NPIX = TILE * TILE;
    constexpr int CPG  = BS / NPIX;
    constexpr int COPT = 24 / CPG;
    constexpr int WPB  = BS / 64;
    constexpr int WPC  = NPIX / 64;
    constexpr int S  = 2 * TILE + 1;
    constexpr int SP = S + 1;
    __shared__ float in_t[CIN][S][SP];
    __shared__ float r1s[WPB][COPT], r2s[WPB][COPT];
    __shared__ float sc[CIN], sh[CIN];
    const int tid = threadIdx.x;
    const int tx = bx % tilesX;
    const int ty = (bx / tilesX) % tilesX;
    const int n  = bx / (tilesX * tilesX);

    if (BNIN) {
        if (tid < CIN) {
            float mu  = pstats[2 * tid] * pinvM;
            float var = pstats[2 * tid + 1] * pinvM - mu * mu;
            float rs  = rsqrtf(var + 1e-5f);
            sc[tid] = rs * pg[tid];
            sh[tid] = pb[tid] - mu * rs * pg[tid];
        }
        __syncthreads();
    }
    const int iy0 = ty * 2 * TILE - 1, ix0 = tx * 2 * TILE - 1;
    for (int idx = tid; idx < CIN * S * S; idx += BS) {
        int ci = idx / (S * S), r = idx % (S * S);
        int ry = r / S, rx = r % S;
        int gy = iy0 + ry, gx = ix0 + rx;
        float v = 0.f;
        if ((unsigned)gy < (unsigned)HIN && (unsigned)gx < (unsigned)WIN) {
            v = in[((size_t)(n * CIN + ci) * HIN + gy) * WIN + gx];
            if (BNIN) v = fmaxf(v * sc[ci] + sh[ci], 0.f);
        }
        in_t[ci][ry][rx] = v;
    }
    __syncthreads();

    const int p   = tid % NPIX;
    const int co0 = __builtin_amdgcn_readfirstlane((tid / NPIX) * COPT);
    const int ly  = (p / TILE) * 2, lx = (p % TILE) * 2;
    float acc[COPT];
#pragma unroll
    for (int c = 0; c < COPT; c++) acc[c] = bias[co0 + c];
    for (int ci = 0; ci < CIN; ci++) {
#pragma unroll
        for (int ky = 0; ky < 3; ky++) {
            const float* row = &in_t[ci][ly + ky][lx];
#pragma unroll
            for (int kx = 0; kx < 3; kx++) {
                float v = row[kx];
#pragma unroll
                for (int c = 0; c < COPT; c++)
                    acc[c] += v * Wg[(((co0 + c) * CIN + ci) * 3 + ky) * 3 + kx];
            }
        }
    }
    const int oy = ty * TILE + p / TILE, ox = tx * TILE + p % TILE;
#pragma unroll
    for (int c = 0; c < COPT; c++)
        out[((size_t)(n * 24 + co0 + c) * HO + oy) * WO + ox] = acc[c];

    const int lane = tid & 63, wv = tid >> 6;
#pragma unroll
    for (int c = 0; c < COPT; c++) {
        float s1 = acc[c], s2 = acc[c] * acc[c];
#pragma unroll
        for (int off = 1; off < 64; off <<= 1) {
            s1 += __shfl_xor(s1, off, 64);
            s2 += __shfl_xor(s2, off, 64);
        }
        if (lane == 0) { r1s[wv][c] = s1; r2s[wv][c] = s2; }
    }
    __syncthreads();
    if (tid < 24) {
        int cg = tid / COPT, slot = tid % COPT;
        float t1 = 0.f, t2 = 0.f;
#pragma unroll
        for (int u = 0; u < WPC; u++) { t1 += r1s[cg * WPC + u][slot]; t2 += r2s[cg * WPC + u][slot]; }
        atomicAdd(&stats[tid * 2],     t1);
        atomicAdd(&stats[tid * 2 + 1], t2);
    }
}

template<int CIN, int TILE, bool BNIN>
__global__ __launch_bounds__(256) void conv_tiled(
    const float* __restrict__ in, const float* __restrict__ Wg,
    const float* __restrict__ bias,
    const float* __restrict__ pstats, const float* __restrict__ pg,
    const float* __restrict__ pb, float pinvM,
    float* __restrict__ out, float* __restrict__ stats,
    int HIN, int WIN, int HO, int WO, int tilesX)
{
    conv_body<CIN, TILE, BNIN, 256>(in, Wg, bias, pstats, pg, pb, pinvM,
                                    out, stats, HIN, WIN, HO, WO, tilesX, blockIdx.x);
}

// ---------------- merged front: lstm (0-31) + conv0 (32-543) + cvt (544-591) ----------------
__global__ __launch_bounds__(1024, 4) void fused_front(
    const int* __restrict__ q, const float* __restrict__ embW,
    const float* __restrict__ Wih, const float* __restrict__ Whh,
    const float* __restrict__ bih, const float* __restrict__ bhh,
    float* __restrict__ qf,
    const float* __restrict__ images, const float* __restrict__ c0W,
    const float* __restrict__ c0b, float* __restrict__ conv0o,
    float* __restrict__ stats,
    const float* __restrict__ gsW, unsigned short* __restrict__ Wbf)
{
    const int bx = blockIdx.x;
    if (bx < 32) {
        lstm_body(q, embW, Wih, Whh, bih, bhh, qf, bx);
    } else if (bx < 544) {
        conv_body<3, 16, false, 1024>(images, c0W, c0b, nullptr, nullptr, nullptr, 0.f,
                                      conv0o, stats, 128, 128, 64, 64, 4, bx - 32);
    } else {
        int i = ((bx - 544) << 10) + threadIdx.x;
#pragma unroll
        for (int u = 0; u < 4; u++) {
            Wbf[i] = f2bf(gsW[i]);
            i += 48 * 1024;
        }
    }
}

// ---------------- A,B,QT projections: 4 blocks per n, LDS-staged g0W ----------------
__global__ __launch_bounds__(256) void abqt_kernel(
    const float* __restrict__ feat,  // (32,24,8,8) raw conv3
    const float* __restrict__ stats, const float* __restrict__ g,
    const float* __restrict__ b, float invM,
    const float* __restrict__ qf,    // (32,128)
    const float* __restrict__ g0W,   // (256,180)
    const float* __restrict__ g0b,
    float* __restrict__ A, float* __restrict__ Bm, float* __restrict__ QT)
{
    const int n = blockIdx.x >> 2, iq = blockIdx.x & 3, k = threadIdx.x;
    __shared__ float wAB[256][53];   // g0W[:, 0:52] staged, padded
    __shared__ float wq[64][128];    // g0W[iq*64 + :, 52:180]
    __shared__ float obj[16][28];
    __shared__ float qs[RNN];
    __shared__ float sc[24], sh[24];
    if (k < 24) {
        float mu  = stats[2 * k] * invM;
        float var = stats[2 * k + 1] * invM - mu * mu;
        float rs  = rsqrtf(var + 1e-5f);
        sc[k] = rs * g[k];
        sh[k] = b[k] - mu * rs * g[k];
    }
    if (k >= 128) qs[k - 128] = qf[n * RNN + (k - 128)];
    for (int idx = k; idx < 256 * 52; idx += 256) {
        int kr = idx / 52, c = idx % 52;
        wAB[kr][c] = g0W[kr * GIN + c];
    }
    for (int idx = k; idx < 64 * 128; idx += 256) {
        int r = idx >> 7, d = idx & 127;
        wq[r][d] = g0W[(((iq << 6) + r)) * GIN + 52 + d];
    }
    __syncthreads();
    for (int idx = k; idx < 24 * 16; idx += 256) {
        int c = idx >> 4, il = idx & 15;
        int i = (iq << 4) + il;
        float v = feat[(n * CDIM + c) * 64 + i];
        obj[il][c] = fmaxf(v * sc[c] + sh[c], 0.f);
    }
    if (k < 16) {
        int i = (iq << 4) + k;
        obj[k][24] = (float)(i & 7)  * (1.f / 7.f);   // xc
        obj[k][25] = (float)(i >> 3) * (1.f / 7.f);   // yc
        obj[k][26] = 0.f; obj[k][27] = 0.f;
    }
    __syncthreads();
    if (k < 64) {
        int kr = (iq << 6) + k;
        float qv = g0b[kr];
#pragma unroll
        for (int d = 0; d < RNN; d++) qv += wq[k][d] * qs[d];
        QT[(n << 8) + kr] = qv;
    }
    float wA[26], wB[26];
#pragma unroll
    for (int c = 0; c < 26; c++) { wA[c] = wAB[k][c]; wB[c] = wAB[k][26 + c]; }
    for (int il = 0; il < 16; il++) {
        const f32x4* op = (const f32x4*)obj[il];
        f32x4 r0 = op[0], r1 = op[1], r2 = op[2], r3 = op[3],
              r4 = op[4], r5 = op[5], r6 = op[6];
        float a = 0.f, bb = 0.f;
#pragma unroll
        for (int p = 0; p < 4; p++) {
            a += wA[p] * r0[p] + wA[4 + p] * r1[p] + wA[8 + p] * r2[p]
               + wA[12 + p] * r3[p] + wA[16 + p] * r4[p] + wA[20 + p] * r5[p];
            bb += wB[p] * r0[p] + wB[4 + p] * r1[p] + wB[8 + p] * r2[p]
                + wB[12 + p] * r3[p] + wB[16 + p] * r4[p] + wB[20 + p] * r5[p];
        }
        a += wA[24] * r6[0] + wA[25] * r6[1];
        bb += wB[24] * r6[0] + wB[25] * r6[1];
        int i = (iq << 4) + il;
        A [(((n << 6) + i) << 8) + k] = a;
        Bm[(((n << 6) + i) << 8) + k] = bb;
    }
}

// ---------------- fused 3x(256->256) g-MLP + pair sum, bf16 MFMA ----------------
// R7 known-good: 256 thr = 4 waves (one col-quarter each, W read ONCE per layer);
// W global->reg + X LDS->reg register-prefetched one kb ahead; no spill at 128 VGPR
__global__ __launch_bounds__(256, 2) void gs_fused(
    const float* __restrict__ A, const float* __restrict__ Bm, const float* __restrict__ QT,
    const unsigned short* __restrict__ Wb,   // (3,256,256) bf16
    const float* __restrict__ gsb,           // (3,256)
    float* __restrict__ partial)             // (1024,256)
{
    __shared__ __align__(16) unsigned short Xs[128 * 256];  // 64 KB
    __shared__ float AQ[2][256];
    __shared__ float biasv[3][256];
    const int raw = blockIdx.x;
    const int bb = (raw & 7) * 128 + (raw >> 3);   // XCD-contiguous: 4 n's per XCD
    const int n = bb >> 5, ip = bb & 31, tid = threadIdx.x;
    const int lane = tid & 63, w = tid >> 6, l15 = lane & 15, lh = lane >> 4;

    {
        float qt = QT[(n << 8) + tid];
        AQ[0][tid] = A[(((n << 6) + ip * 2)     << 8) + tid] + qt;
        AQ[1][tid] = A[(((n << 6) + ip * 2 + 1) << 8) + tid] + qt;
        biasv[0][tid] = gsb[tid];
        biasv[1][tid] = gsb[256 + tid];
        biasv[2][tid] = gsb[512 + tid];
    }
    __syncthreads();

    // build h0 = relu(A_i + B_j + QT) into Xs; 128 rows x 32 col-groups
#pragma unroll
    for (int it = 0; it < 16; it++) {
        int task = tid + (it << 8);
        int r = task >> 5, g = task & 31;
        int isub = r >> 6, j = r & 63;
        const f32x4* bp = (const f32x4*)(Bm + (((n << 6) + j) << 8) + (g << 3));
        f32x4 b0 = bp[0], b1 = bp[1];
        u16x8 pk;
        int c0 = g << 3;
#pragma unroll
        for (int p = 0; p < 4; p++) {
            pk[p]     = f2bf(fmaxf(b0[p] + AQ[isub][c0 + p], 0.f));
            pk[p + 4] = f2bf(fmaxf(b1[p] + AQ[isub][c0 + 4 + p], 0.f));
        }
        *(u16x8*)((char*)Xs + r * 512 + ((g ^ (r & 7)) << 4)) = pk;
    }

    f32x4 acc[4][8];                 // [col-tile][row-slab]
    const f32x4 zero4 = {0.f, 0.f, 0.f, 0.f};
    bf16x8 wa[4], wn[4], xa[8], xn[8];
    for (int layer = 0; layer < 3; layer++) {
#pragma unroll
        for (int tc = 0; tc < 4; tc++)
#pragma unroll
            for (int sl = 0; sl < 8; sl++) acc[tc][sl] = zero4;
        // per-lane W base: row = w*64 + tc*16 + l15, K offset lh*8 (+kb*32)
        const unsigned short* wbase = Wb + (layer << 16)
                                    + (((w << 6) + l15) << 8) + (lh << 3);
        // prefetch W for kb=0 BEFORE the barrier (independent of Xs)
#pragma unroll
        for (int tc = 0; tc < 4; tc++) wa[tc] = *(const bf16x8*)(wbase + (tc << 12));
        __syncthreads();   // Xs ready (build or previous writeback)
        // prefetch X for kb=0
#pragma unroll
        for (int sl = 0; sl < 8; sl++) {
            int ar = (sl << 4) + l15;
            int au = lh ^ (ar & 7);
            xa[sl] = *(const bf16x8*)((const char*)Xs + ar * 512 + (au << 4));
        }
#pragma unroll
        for (int kb = 0; kb < 8; kb++) {
            if (kb < 7) {
#pragma unroll
                for (int tc = 0; tc < 4; tc++)
                    wn[tc] = *(const bf16x8*)(wbase + (tc << 12) + ((kb + 1) << 5));
#pragma unroll
                for (int sl = 0; sl < 8; sl++) {
                    int ar = (sl << 4) + l15;
                    int au = (((kb + 1) << 2) + lh) ^ (ar & 7);
                    xn[sl] = *(const bf16x8*)((const char*)Xs + ar * 512 + (au << 4));
                }
            }
#pragma unroll
            for (int tc = 0; tc < 4; tc++)
#pragma unroll
                for (int sl = 0; sl < 8; sl++)
                    acc[tc][sl] = __builtin_amdgcn_mfma_f32_16x16x32_bf16(
                        wa[tc], xa[sl], acc[tc][sl], 0, 0, 0);
            if (kb < 7) {
#pragma unroll
                for (int tc = 0; tc < 4; tc++) wa[tc] = wn[tc];
#pragma unroll
                for (int sl = 0; sl < 8; sl++) xa[sl] = xn[sl];
            }
        }
        if (layer < 2) {
            __syncthreads();  // all waves done reading Xs before overwrite
#pragma unroll
            for (int tc = 0; tc < 4; tc++) {
                int c0 = (w << 6) + (tc << 4) + (lh << 2);
                float b0 = biasv[layer][c0],     b1 = biasv[layer][c0 + 1];
                float b2 = biasv[layer][c0 + 2], b3 = biasv[layer][c0 + 3];
#pragma unroll
                for (int sl = 0; sl < 8; sl++) {
                    int row = (sl << 4) + l15;
                    s16x4 pk;
                    pk[0] = (short)f2bf(fmaxf(acc[tc][sl][0] + b0, 0.f));
                    pk[1] = (short)f2bf(fmaxf(acc[tc][sl][1] + b1, 0.f));
                    pk[2] = (short)f2bf(fmaxf(acc[tc][sl][2] + b2, 0.f));
                    pk[3] = (short)f2bf(fmaxf(acc[tc][sl][3] + b3, 0.f));
                    *(s16x4*)((char*)Xs + row * 512 + (((c0 >> 3) ^ (row & 7)) << 4)
                              + ((c0 & 7) << 1)) = pk;
                }
            }
        } else {
            // final: relu + sum over the block's 128 pair-rows -> partial[bb][col]
#pragma unroll
            for (int tc = 0; tc < 4; tc++) {
                int c0 = (w << 6) + (tc << 4) + (lh << 2);
                f32x4 cs;
#pragma unroll
                for (int p = 0; p < 4; p++) {
                    float bv = biasv[2][c0 + p];
                    float s = 0.f;
#pragma unroll
                    for (int sl = 0; sl < 8; sl++) s += fmaxf(acc[tc][sl][p] + bv, 0.f);
                    s += __shfl_xor(s, 1, 64);
                    s += __shfl_xor(s, 2, 64);
                    s += __shfl_xor(s, 4, 64);
                    s += __shfl_xor(s, 8, 64);
                    cs[p] = s;
                }
                if (l15 == 0) *(f32x4*)(partial + (size_t)bb * 256 + c0) = cs;
            }
        }
    }
}

// ---------------- f-MLP: thread-per-row GEMV, vec4 + deep ILP ----------------
__device__ __forceinline__ float dot256(const float* __restrict__ wr,
                                        const float* __restrict__ x)
{
    const f32x4* w4 = (const f32x4*)wr;
    const f32x4* x4 = (const f32x4*)x;
    f32x4 a0 = {0.f, 0.f, 0.f, 0.f}, a1 = a0, a2 = a0, a3 = a0;
#pragma unroll 8
    for (int c = 0; c < 64; c += 4) {
        f32x4 w0 = w4[c], w1 = w4[c + 1], w2 = w4[c + 2], w3 = w4[c + 3];
        f32x4 x0 = x4[c], x1 = x4[c + 1], x2 = x4[c + 2], x3 = x4[c + 3];
        a0 += w0 * x0; a1 += w1 * x1; a2 += w2 * x2; a3 += w3 * x3;
    }
    f32x4 a = (a0 + a1) + (a2 + a3);
    return (a[0] + a[1]) + (a[2] + a[3]);
}

__global__ __launch_bounds__(256) void f_mlp(
    const float* __restrict__ partial,
    const float* __restrict__ f0W, const float* __restrict__ f0b,
    const float* __restrict__ f1W, const float* __restrict__ f1b,
    const float* __restrict__ f2W, const float* __restrict__ f2b,
    float* __restrict__ out)
{
    const int n = blockIdx.x, k = threadIdx.x;
    __shared__ float fin[256], h1[256], h2[256];
    const float* pb = partial + (size_t)(n * 32) * 256 + k;
    float s0 = 0.f, s1 = 0.f, s2 = 0.f, s3 = 0.f;
#pragma unroll
    for (int b = 0; b < 32; b += 4) {
        s0 += pb[(b + 0) << 8];
        s1 += pb[(b + 1) << 8];
        s2 += pb[(b + 2) << 8];
        s3 += pb[(b + 3) << 8];
    }
    fin[k] = (s0 + s1) + (s2 + s3);
    __syncthreads();
    h1[k] = fmaxf(dot256(f0W + (k << 8), fin) + f0b[k], 0.f);
    __syncthreads();
    h2[k] = fmaxf(dot256(f1W + (k << 8), h1) + f1b[k], 0.f);
    __syncthreads();
    if (k < 32)
        out[(n << 5) + k] = dot256(f2W + (k << 8), h2) + f2b[k];
}

extern "C" void kernel_launch(void* const* d_in, const int* in_sizes, int n_in,
                              void* d_out, int out_size, void* d_ws, size_t ws_size,
                              hipStream_t stream)
{
    const int*   questions = (const int*)  d_in[0];
    const float* images = (const float*)d_in[1];
    const float* embW   = (const float*)d_in[2];
    const float* Wih    = (const float*)d_in[3];
    const float* Whh    = (const float*)d_in[4];
    const float* bih    = (const float*)d_in[5];
    const float* bhh    = (const float*)d_in[6];
    const float* c0W    = (const float*)d_in[7];
    const float* c0b    = (const float*)d_in[8];
    const float* bn0g   = (const float*)d_in[9];
    const float* bn0b   = (const float*)d_in[10];
    const float* csW    = (const float*)d_in[11];
    const float* csb    = (const float*)d_in[12];
    const float* bnsg   = (const float*)d_in[13];
    const float* bnsb   = (const float*)d_in[14];
    const float* g0W    = (const float*)d_in[15];
    const float* g0b    = (const float*)d_in[16];
    const float* gsW    = (const float*)d_in[17];
    const float* gsb    = (const float*)d_in[18];
    const float* f0W    = (const float*)d_in[19];
    const float* f0b    = (const float*)d_in[20];
    const float* f1W    = (const float*)d_in[21];
    const float* f1b    = (const float*)d_in[22];
    const float* f2W    = (const float*)d_in[23];
    const float* f2b    = (const float*)d_in[24];

    float* ws  = (float*)d_ws;
    float* out = (float*)d_out;

    // workspace layout (floats)
    float* conv0o = ws;                 // 3,145,728  (32,24,64,64)
    float* conv1o = ws + 3145728;       //   786,432  (32,24,32,32)
    float* conv2o = ws + 3932160;       //   196,608  (32,24,16,16)
    float* conv3o = ws + 4128768;       //    49,152  (32,24,8,8)
    float* stats  = ws + 4177920;       //       192
    float* qf     = ws + 4178112;       //     4,096  (32,128)
    unsigned short* Wbf = (unsigned short*)(ws + 4182208);  // 196,608 bf16
    // overlay into conv0o region (dead after conv1 consumes it):
    float* Abuf   = ws;                 //   524,288  (32,64,256)
    float* Bbuf   = ws + 524288;        //   524,288
    float* QTb    = ws + 1048576;       //     8,192  (32,256)
    float* part   = ws + 1155072;       //   262,144  (1024,256)

    hipMemsetAsync(stats, 0, 192 * sizeof(float), stream);

    // lstm (32 blocks, k-split) + conv0 (512) + gsW->bf16 cvt (48)
    fused_front<<<592, 1024, 0, stream>>>(questions, embW, Wih, Whh, bih, bhh, qf,
                                          images, c0W, c0b, conv0o, stats, gsW, Wbf);
    // conv1: BN0 applied on load; out (32,24,32,32)
    conv_tiled<24, 8, true><<<512, 256, 0, stream>>>(
        conv0o, csW, csb, stats, bn0g, bn0b, 1.f / 131072.f,
        conv1o, stats + 48, 64, 64, 32, 32, 4);
    // conv2: out (32,24,16,16)
    conv_tiled<24, 8, true><<<128, 256, 0, stream>>>(
        conv1o, csW + 5184, csb + 24, stats + 48, bnsg, bnsb, 1.f / 32768.f,
        conv2o, stats + 96, 32, 32, 16, 16, 2);
    // conv3: out (32,24,8,8)
    conv_tiled<24, 8, true><<<32, 256, 0, stream>>>(
        conv2o, csW + 10368, csb + 48, stats + 96, bnsg + 24, bnsb + 24, 1.f / 8192.f,
        conv3o, stats + 144, 16, 16, 8, 8, 1);

    abqt_kernel<<<128, 256, 0, stream>>>(conv3o, stats + 144, bnsg + 48, bnsb + 48,
                                         1.f / 2048.f, qf, g0W, g0b, Abuf, Bbuf, QTb);
    gs_fused<<<1024, 256, 0, stream>>>(Abuf, Bbuf, QTb, Wbf, gsb, part);
    f_mlp<<<32, 256, 0, stream>>>(part, f0W, f0b, f1W, f1b, f2W, f2b, out);
}

// Round 11
// 273.685 us; speedup vs baseline: 1.6329x; 1.0925x over previous
//
#include <hip/hip_runtime.h>

// ---------- model dims ----------
#define NB   32
#define TT   46
#define RNN  128
#define CDIM 24
#define GD   256
#define GIN  180

typedef __attribute__((ext_vector_type(8))) short  bf16x8;
typedef __attribute__((ext_vector_type(4))) short  s16x4;
typedef __attribute__((ext_vector_type(8))) unsigned short u16x8;
typedef __attribute__((ext_vector_type(4))) float  f32x4;

__device__ __forceinline__ unsigned short f2bf(float v) {
    unsigned u = __float_as_uint(v);
    u = u + 0x7fffu + ((u >> 16) & 1u);   // RNE
    return (unsigned short)(u >> 16);
}

__device__ __forceinline__ float fast_sigmoid(float x) {
    return 1.f / (1.f + __expf(-x));
}
__device__ __forceinline__ float fast_tanh(float x) {
    // 1 - 2/(e^{2x}+1); safe at +/-inf
    return 1.f - 2.f / (__expf(2.f * x) + 1.f);
}

// ---------------- LSTM body (512 threads, one block per n) ----------------
// weights register-resident (f32x4); REQUIRES >=200 VGPR -> host kernel must
// use __launch_bounds__(512, 1) so the allocator doesn't cap at 128 and spill
__device__ __forceinline__ void lstm_body(
    const int* __restrict__ q, const float* __restrict__ embW,
    const float* __restrict__ Wih, const float* __restrict__ Whh,
    const float* __restrict__ bih, const float* __restrict__ bhh,
    float* __restrict__ qf, int n)
{
    const int tid = threadIdx.x;
    __shared__ __align__(16) float xs[32], hs[RNN];
    __shared__ float zg[512];
    f32x4 wih[8], whh[32];
    {
        const f32x4* wp = (const f32x4*)(Wih + tid * 32);
#pragma unroll
        for (int j = 0; j < 8; j++) wih[j] = wp[j];
        const f32x4* hp = (const f32x4*)(Whh + tid * RNN);
#pragma unroll
        for (int j = 0; j < 32; j++) whh[j] = hp[j];
    }
    const float bias = bih[tid] + bhh[tid];
    float creg = 0.f;
    if (tid < RNN) hs[tid] = 0.f;
    float xr = (tid < 32) ? embW[q[n * TT] * 32 + tid] : 0.f;
    __syncthreads();
    for (int t = 0; t < TT; t++) {
        if (tid < 32) xs[tid] = xr;
        __syncthreads();           // xs ready, hs ready
        if (tid < 32 && t + 1 < TT) xr = embW[q[n * TT + t + 1] * 32 + tid];  // prefetch
        const f32x4* h4 = (const f32x4*)hs;
        const f32x4* x4 = (const f32x4*)xs;
        f32x4 a0 = {0.f, 0.f, 0.f, 0.f}, a1 = a0, a2 = a0, a3 = a0;
#pragma unroll
        for (int j = 0; j < 8; j += 4) {
            a0 += wih[j] * x4[j];     a1 += wih[j + 1] * x4[j + 1];
            a2 += wih[j + 2] * x4[j + 2]; a3 += wih[j + 3] * x4[j + 3];
        }
#pragma unroll
        for (int j = 0; j < 32; j += 4) {
            a0 += whh[j] * h4[j];     a1 += whh[j + 1] * h4[j + 1];
            a2 += whh[j + 2] * h4[j + 2]; a3 += whh[j + 3] * h4[j + 3];
        }
        f32x4 a = (a0 + a1) + (a2 + a3);
        zg[tid] = bias + ((a[0] + a[1]) + (a[2] + a[3]));
        __syncthreads();
        if (tid < RNN) {
            float ig = fast_sigmoid(zg[tid]);
            float fg = fast_sigmoid(zg[RNN + tid]);
            float gg = fast_tanh(zg[2 * RNN + tid]);
            float og = fast_sigmoid(zg[3 * RNN + tid]);
            float cn = fg * creg + ig * gg;
            creg = cn;
            hs[tid] = og * fast_tanh(cn);
        }
        __syncthreads();
    }
    if (tid < RNN) qf[n * RNN + tid] = hs[tid];
}

// ---------------- tiled conv 3x3 s2 p1 body ----------------
template<int CIN, int TILE, bool BNIN, int BS>
__device__ __forceinline__ void conv_body(
    const float* __restrict__ in, const float* __restrict__ Wg,
    const float* __restrict__ bias,
    const float* __restrict__ pstats, const float* __restrict__ pg,
    const float* __restrict__ pb, float pinvM,
    float* __restrict__ out, float* __restrict__ stats,
    int HIN, int WIN, int HO, int WO, int tilesX, int bx)
{
    constexpr int NPIX = TILE * TILE;
    constexpr int CPG  = BS / NPIX;
    constexpr int COPT = 24 / CPG;
    constexpr int WPB  = BS / 64;
    constexpr int WPC  = NPIX / 64;
    constexpr int S  = 2 * TILE + 1;
    constexpr int SP = S + 1;
    __shared__ float in_t[CIN][S][SP];
    __shared__ float r1s[WPB][COPT], r2s[WPB][COPT];
    __shared__ float sc[CIN], sh[CIN];
    const int tid = threadIdx.x;
    const int tx = bx % tilesX;
    const int ty = (bx / tilesX) % tilesX;
    const int n  = bx / (tilesX * tilesX);

    if (BNIN) {
        if (tid < CIN) {
            float mu  = pstats[2 * tid] * pinvM;
            float var = pstats[2 * tid + 1] * pinvM - mu * mu;
            float rs  = rsqrtf(var + 1e-5f);
            sc[tid] = rs * pg[tid];
            sh[tid] = pb[tid] - mu * rs * pg[tid];
        }
        __syncthreads();
    }
    const int iy0 = ty * 2 * TILE - 1, ix0 = tx * 2 * TILE - 1;
    for (int idx = tid; idx < CIN * S * S; idx += BS) {
        int ci = idx / (S * S), r = idx % (S * S);
        int ry = r / S, rx = r % S;
        int gy = iy0 + ry, gx = ix0 + rx;
        float v = 0.f;
        if ((unsigned)gy < (unsigned)HIN && (unsigned)gx < (unsigned)WIN) {
            v = in[((size_t)(n * CIN + ci) * HIN + gy) * WIN + gx];
            if (BNIN) v = fmaxf(v * sc[ci] + sh[ci], 0.f);
        }
        in_t[ci][ry][rx] = v;
    }
    __syncthreads();

    const int p   = tid % NPIX;
    const int co0 = __builtin_amdgcn_readfirstlane((tid / NPIX) * COPT);
    const int ly  = (p / TILE) * 2, lx = (p % TILE) * 2;
    float acc[COPT];
#pragma unroll
    for (int c = 0; c < COPT; c++) acc[c] = bias[co0 + c];
    for (int ci = 0; ci < CIN; ci++) {
#pragma unroll
        for (int ky = 0; ky < 3; ky++) {
            const float* row = &in_t[ci][ly + ky][lx];
#pragma unroll
            for (int kx = 0; kx < 3; kx++) {
                float v = row[kx];
#pragma unroll
                for (int c = 0; c < COPT; c++)
                    acc[c] += v * Wg[(((co0 + c) * CIN + ci) * 3 + ky) * 3 + kx];
            }
        }
    }
    const int oy = ty * TILE + p / TILE, ox = tx * TILE + p % TILE;
#pragma unroll
    for (int c = 0; c < COPT; c++)
        out[((size_t)(n * 24 + co0 + c) * HO + oy) * WO + ox] = acc[c];

    const int lane = tid & 63, wv = tid >> 6;
#pragma unroll
    for (int c = 0; c < COPT; c++) {
        float s1 = acc[c], s2 = acc[c] * acc[c];
#pragma unroll
        for (int off = 1; off < 64; off <<= 1) {
            s1 += __shfl_xor(s1, off, 64);
            s2 += __shfl_xor(s2, off, 64);
        }
        if (lane == 0) { r1s[wv][c] = s1; r2s[wv][c] = s2; }
    }
    __syncthreads();
    if (tid < 24) {
        int cg = tid / COPT, slot = tid % COPT;
        float t1 = 0.f, t2 = 0.f;
#pragma unroll
        for (int u = 0; u < WPC; u++) { t1 += r1s[cg * WPC + u][slot]; t2 += r2s[cg * WPC + u][slot]; }
        atomicAdd(&stats[tid * 2],     t1);
        atomicAdd(&stats[tid * 2 + 1], t2);
    }
}

template<int CIN, int TILE, bool BNIN>
__global__ __launch_bounds__(256) void conv_tiled(
    const float* __restrict__ in, const float* __restrict__ Wg,
    const float* __restrict__ bias,
    const float* __restrict__ pstats, const float* __restrict__ pg,
    const float* __restrict__ pb, float pinvM,
    float* __restrict__ out, float* __restrict__ stats,
    int HIN, int WIN, int HO, int WO, int tilesX)
{
    conv_body<CIN, TILE, BNIN, 256>(in, Wg, bias, pstats, pg, pb, pinvM,
                                    out, stats, HIN, WIN, HO, WO, tilesX, blockIdx.x);
}

// ---------------- merged front: lstm (0-31) + conv0 (32-543) + cvt (544-639) ----------------
// launch_bounds(512, 1): VGPR cap 512 so the LSTM weights NEVER spill
__global__ __launch_bounds__(512, 1) void fused_front(
    const int* __restrict__ q, const float* __restrict__ embW,
    const float* __restrict__ Wih, const float* __restrict__ Whh,
    const float* __restrict__ bih, const float* __restrict__ bhh,
    float* __restrict__ qf,
    const float* __restrict__ images, const float* __restrict__ c0W,
    const float* __restrict__ c0b, float* __restrict__ conv0o,
    float* __restrict__ stats,
    const float* __restrict__ gsW, unsigned short* __restrict__ Wbf)
{
    const int bx = blockIdx.x;
    if (bx < 32) {
        lstm_body(q, embW, Wih, Whh, bih, bhh, qf, bx);
    } else if (bx < 544) {
        conv_body<3, 16, false, 512>(images, c0W, c0b, nullptr, nullptr, nullptr, 0.f,
                                     conv0o, stats, 128, 128, 64, 64, 4, bx - 32);
    } else {
        int i = ((bx - 544) << 9) + threadIdx.x;
#pragma unroll
        for (int u = 0; u < 4; u++) {
            Wbf[i] = f2bf(gsW[i]);
            i += 96 * 512;
        }
    }
}

// ---------------- A,B,QT projections: 4 blocks per n, LDS-staged g0W ----------------
__global__ __launch_bounds__(256) void abqt_kernel(
    const float* __restrict__ feat,  // (32,24,8,8) raw conv3
    const float* __restrict__ stats, const float* __restrict__ g,
    const float* __restrict__ b, float invM,
    const float* __restrict__ qf,    // (32,128)
    const float* __restrict__ g0W,   // (256,180)
    const float* __restrict__ g0b,
    float* __restrict__ A, float* __restrict__ Bm, float* __restrict__ QT)
{
    const int n = blockIdx.x >> 2, iq = blockIdx.x & 3, k = threadIdx.x;
    __shared__ float wAB[256][53];   // g0W[:, 0:52] staged, padded
    __shared__ float wq[64][128];    // g0W[iq*64 + :, 52:180]
    __shared__ float obj[16][28];
    __shared__ float qs[RNN];
    __shared__ float sc[24], sh[24];
    if (k < 24) {
        float mu  = stats[2 * k] * invM;
        float var = stats[2 * k + 1] * invM - mu * mu;
        float rs  = rsqrtf(var + 1e-5f);
        sc[k] = rs * g[k];
        sh[k] = b[k] - mu * rs * g[k];
    }
    if (k >= 128) qs[k - 128] = qf[n * RNN + (k - 128)];
    for (int idx = k; idx < 256 * 52; idx += 256) {
        int kr = idx / 52, c = idx % 52;
        wAB[kr][c] = g0W[kr * GIN + c];
    }
    for (int idx = k; idx < 64 * 128; idx += 256) {
        int r = idx >> 7, d = idx & 127;
        wq[r][d] = g0W[(((iq << 6) + r)) * GIN + 52 + d];
    }
    __syncthreads();
    for (int idx = k; idx < 24 * 16; idx += 256) {
        int c = idx >> 4, il = idx & 15;
        int i = (iq << 4) + il;
        float v = feat[(n * CDIM + c) * 64 + i];
        obj[il][c] = fmaxf(v * sc[c] + sh[c], 0.f);
    }
    if (k < 16) {
        int i = (iq << 4) + k;
        obj[k][24] = (float)(i & 7)  * (1.f / 7.f);   // xc
        obj[k][25] = (float)(i >> 3) * (1.f / 7.f);   // yc
        obj[k][26] = 0.f; obj[k][27] = 0.f;
    }
    __syncthreads();
    if (k < 64) {
        int kr = (iq << 6) + k;
        float qv = g0b[kr];
#pragma unroll
        for (int d = 0; d < RNN; d++) qv += wq[k][d] * qs[d];
        QT[(n << 8) + kr] = qv;
    }
    float wA[26], wB[26];
#pragma unroll
    for (int c = 0; c < 26; c++) { wA[c] = wAB[k][c]; wB[c] = wAB[k][26 + c]; }
    for (int il = 0; il < 16; il++) {
        const f32x4* op = (const f32x4*)obj[il];
        f32x4 r0 = op[0], r1 = op[1], r2 = op[2], r3 = op[3],
              r4 = op[4], r5 = op[5], r6 = op[6];
        float a = 0.f, bb = 0.f;
#pragma unroll
        for (int p = 0; p < 4; p++) {
            a += wA[p] * r0[p] + wA[4 + p] * r1[p] + wA[8 + p] * r2[p]
               + wA[12 + p] * r3[p] + wA[16 + p] * r4[p] + wA[20 + p] * r5[p];
            bb += wB[p] * r0[p] + wB[4 + p] * r1[p] + wB[8 + p] * r2[p]
                + wB[12 + p] * r3[p] + wB[16 + p] * r4[p] + wB[20 + p] * r5[p];
        }
        a += wA[24] * r6[0] + wA[25] * r6[1];
        bb += wB[24] * r6[0] + wB[25] * r6[1];
        int i = (iq << 4) + il;
        A [(((n << 6) + i) << 8) + k] = a;
        Bm[(((n << 6) + i) << 8) + k] = bb;
    }
}

// ---------------- fused 3x(256->256) g-MLP + pair sum, bf16 MFMA ----------------
// R7 K-loop (proven 68.5 us, no spill) + build phase reads A/QT direct from
// global into hoisted registers (g = tid&31 invariant) -> no AQ LDS, no
// 16-way-conflicted scalar reads, one less barrier
__global__ __launch_bounds__(256, 2) void gs_fused(
    const float* __restrict__ A, const float* __restrict__ Bm, const float* __restrict__ QT,
    const unsigned short* __restrict__ Wb,   // (3,256,256) bf16
    const float* __restrict__ gsb,           // (3,256)
    float* __restrict__ partial)             // (1024,256)
{
    __shared__ __align__(16) unsigned short Xs[128 * 256];  // 64 KB
    __shared__ float biasv[3][256];
    const int raw = blockIdx.x;
    const int bb = (raw & 7) * 128 + (raw >> 3);   // XCD-contiguous: 4 n's per XCD
    const int n = bb >> 5, ip = bb & 31, tid = threadIdx.x;
    const int lane = tid & 63, w = tid >> 6, l15 = lane & 15, lh = lane >> 4;

    biasv[0][tid] = gsb[tid];
    biasv[1][tid] = gsb[256 + tid];
    biasv[2][tid] = gsb[512 + tid];

    // build h0 = relu(A_i + B_j + QT) into Xs; per-thread col-group g fixed
    {
        const int g = tid & 31, c0 = g << 3;
        const f32x4* qtp = (const f32x4*)(QT + (n << 8) + c0);
        f32x4 qta = qtp[0], qtb = qtp[1];
        const f32x4* a0p = (const f32x4*)(A + (((n << 6) + ip * 2)     << 8) + c0);
        const f32x4* a1p = (const f32x4*)(A + (((n << 6) + ip * 2 + 1) << 8) + c0);
        f32x4 aq0a = a0p[0] + qta, aq0b = a0p[1] + qtb;
        f32x4 aq1a = a1p[0] + qta, aq1b = a1p[1] + qtb;
#pragma unroll
        for (int it = 0; it < 16; it++) {
            int r = (tid >> 5) + (it << 3);
            int j = r & 63;
            f32x4 aa = (it < 8) ? aq0a : aq1a;
            f32x4 ab = (it < 8) ? aq0b : aq1b;
            const f32x4* bp = (const f32x4*)(Bm + (((n << 6) + j) << 8) + c0);
            f32x4 b0 = bp[0], b1 = bp[1];
            u16x8 pk;
#pragma unroll
            for (int p = 0; p < 4; p++) {
                pk[p]     = f2bf(fmaxf(b0[p] + aa[p], 0.f));
                pk[p + 4] = f2bf(fmaxf(b1[p] + ab[p], 0.f));
            }
            *(u16x8*)((char*)Xs + r * 512 + ((g ^ (r & 7)) << 4)) = pk;
        }
    }

    f32x4 acc[4][8];                 // [col-tile][row-slab]
    const f32x4 zero4 = {0.f, 0.f, 0.f, 0.f};
    bf16x8 wa[4], wn[4], xa[8], xn[8];
    for (int layer = 0; layer < 3; layer++) {
#pragma unroll
        for (int tc = 0; tc < 4; tc++)
#pragma unroll
            for (int sl = 0; sl < 8; sl++) acc[tc][sl] = zero4;
        // per-lane W base: row = w*64 + tc*16 + l15, K offset lh*8 (+kb*32)
        const unsigned short* wbase = Wb + (layer << 16)
                                    + (((w << 6) + l15) << 8) + (lh << 3);
        // prefetch W for kb=0 BEFORE the barrier (independent of Xs)
#pragma unroll
        for (int tc = 0; tc < 4; tc++) wa[tc] = *(const bf16x8*)(wbase + (tc << 12));
        __syncthreads();   // Xs ready (build or previous writeback)
        // prefetch X for kb=0
#pragma unroll
        for (int sl = 0; sl < 8; sl++) {
            int ar = (sl << 4) + l15;
            int au = lh ^ (ar & 7);
            xa[sl] = *(const bf16x8*)((const char*)Xs + ar * 512 + (au << 4));
        }
#pragma unroll
        for (int kb = 0; kb < 8; kb++) {
            if (kb < 7) {
#pragma unroll
                for (int tc = 0; tc < 4; tc++)
                    wn[tc] = *(const bf16x8*)(wbase + (tc << 12) + ((kb + 1) << 5));
#pragma unroll
                for (int sl = 0; sl < 8; sl++) {
                    int ar = (sl << 4) + l15;
                    int au = (((kb + 1) << 2) + lh) ^ (ar & 7);
                    xn[sl] = *(const bf16x8*)((const char*)Xs + ar * 512 + (au << 4));
                }
            }
#pragma unroll
            for (int tc = 0; tc < 4; tc++)
#pragma unroll
                for (int sl = 0; sl < 8; sl++)
                    acc[tc][sl] = __builtin_amdgcn_mfma_f32_16x16x32_bf16(
                        wa[tc], xa[sl], acc[tc][sl], 0, 0, 0);
            if (kb < 7) {
#pragma unroll
                for (int tc = 0; tc < 4; tc++) wa[tc] = wn[tc];
#pragma unroll
                for (int sl = 0; sl < 8; sl++) xa[sl] = xn[sl];
            }
        }
        if (layer < 2) {
            __syncthreads();  // all waves done reading Xs before overwrite
#pragma unroll
            for (int tc = 0; tc < 4; tc++) {
                int c0 = (w << 6) + (tc << 4) + (lh << 2);
                float b0 = biasv[layer][c0],     b1 = biasv[layer][c0 + 1];
                float b2 = biasv[layer][c0 + 2], b3 = biasv[layer][c0 + 3];
#pragma unroll
                for (int sl = 0; sl < 8; sl++) {
                    int row = (sl << 4) + l15;
                    s16x4 pk;
                    pk[0] = (short)f2bf(fmaxf(acc[tc][sl][0] + b0, 0.f));
                    pk[1] = (short)f2bf(fmaxf(acc[tc][sl][1] + b1, 0.f));
                    pk[2] = (short)f2bf(fmaxf(acc[tc][sl][2] + b2, 0.f));
                    pk[3] = (short)f2bf(fmaxf(acc[tc][sl][3] + b3, 0.f));
                    *(s16x4*)((char*)Xs + row * 512 + (((c0 >> 3) ^ (row & 7)) << 4)
                              + ((c0 & 7) << 1)) = pk;
                }
            }
        } else {
            // final: relu + sum over the block's 128 pair-rows -> partial[bb][col]
#pragma unroll
            for (int tc = 0; tc < 4; tc++) {
                int c0 = (w << 6) + (tc << 4) + (lh << 2);
                f32x4 cs;
#pragma unroll
                for (int p = 0; p < 4; p++) {
                    float bv = biasv[2][c0 + p];
                    float s = 0.f;
#pragma unroll
                    for (int sl = 0; sl < 8; sl++) s += fmaxf(acc[tc][sl][p] + bv, 0.f);
                    s += __shfl_xor(s, 1, 64);
                    s += __shfl_xor(s, 2, 64);
                    s += __shfl_xor(s, 4, 64);
                    s += __shfl_xor(s, 8, 64);
                    cs[p] = s;
                }
                if (l15 == 0) *(f32x4*)(partial + (size_t)bb * 256 + c0) = cs;
            }
        }
    }
}

// ---------------- f-MLP: thread-per-row GEMV, vec4 + deep ILP ----------------
__device__ __forceinline__ float dot256(const float* __restrict__ wr,
                                        const float* __restrict__ x)
{
    const f32x4* w4 = (const f32x4*)wr;
    const f32x4* x4 = (const f32x4*)x;
    f32x4 a0 = {0.f, 0.f, 0.f, 0.f}, a1 = a0, a2 = a0, a3 = a0;
#pragma unroll 8
    for (int c = 0; c < 64; c += 4) {
        f32x4 w0 = w4[c], w1 = w4[c + 1], w2 = w4[c + 2], w3 = w4[c + 3];
        f32x4 x0 = x4[c], x1 = x4[c + 1], x2 = x4[c + 2], x3 = x4[c + 3];
        a0 += w0 * x0; a1 += w1 * x1; a2 += w2 * x2; a3 += w3 * x3;
    }
    f32x4 a = (a0 + a1) + (a2 + a3);
    return (a[0] + a[1]) + (a[2] + a[3]);
}

__global__ __launch_bounds__(256) void f_mlp(
    const float* __restrict__ partial,
    const float* __restrict__ f0W, const float* __restrict__ f0b,
    const float* __restrict__ f1W, const float* __restrict__ f1b,
    const float* __restrict__ f2W, const float* __restrict__ f2b,
    float* __restrict__ out)
{
    const int n = blockIdx.x, k = threadIdx.x;
    __shared__ float fin[256], h1[256], h2[256];
    const float* pb = partial + (size_t)(n * 32) * 256 + k;
    float s0 = 0.f, s1 = 0.f, s2 = 0.f, s3 = 0.f;
#pragma unroll
    for (int b = 0; b < 32; b += 4) {
        s0 += pb[(b + 0) << 8];
        s1 += pb[(b + 1) << 8];
        s2 += pb[(b + 2) << 8];
        s3 += pb[(b + 3) << 8];
    }
    fin[k] = (s0 + s1) + (s2 + s3);
    __syncthreads();
    h1[k] = fmaxf(dot256(f0W + (k << 8), fin) + f0b[k], 0.f);
    __syncthreads();
    h2[k] = fmaxf(dot256(f1W + (k << 8), h1) + f1b[k], 0.f);
    __syncthreads();
    if (k < 32)
        out[(n << 5) + k] = dot256(f2W + (k << 8), h2) + f2b[k];
}

extern "C" void kernel_launch(void* const* d_in, const int* in_sizes, int n_in,
                              void* d_out, int out_size, void* d_ws, size_t ws_size,
                              hipStream_t stream)
{
    const int*   questions = (const int*)  d_in[0];
    const float* images = (const float*)d_in[1];
    const float* embW   = (const float*)d_in[2];
    const float* Wih    = (const float*)d_in[3];
    const float* Whh    = (const float*)d_in[4];
    const float* bih    = (const float*)d_in[5];
    const float* bhh    = (const float*)d_in[6];
    const float* c0W    = (const float*)d_in[7];
    const float* c0b    = (const float*)d_in[8];
    const float* bn0g   = (const float*)d_in[9];
    const float* bn0b   = (const float*)d_in[10];
    const float* csW    = (const float*)d_in[11];
    const float* csb    = (const float*)d_in[12];
    const float* bnsg   = (const float*)d_in[13];
    const float* bnsb   = (const float*)d_in[14];
    const float* g0W    = (const float*)d_in[15];
    const float* g0b    = (const float*)d_in[16];
    const float* gsW    = (const float*)d_in[17];
    const float* gsb    = (const float*)d_in[18];
    const float* f0W    = (const float*)d_in[19];
    const float* f0b    = (const float*)d_in[20];
    const float* f1W    = (const float*)d_in[21];
    const float* f1b    = (const float*)d_in[22];
    const float* f2W    = (const float*)d_in[23];
    const float* f2b    = (const float*)d_in[24];

    float* ws  = (float*)d_ws;
    float* out = (float*)d_out;

    // workspace layout (floats)
    float* conv0o = ws;                 // 3,145,728  (32,24,64,64)
    float* conv1o = ws + 3145728;       //   786,432  (32,24,32,32)
    float* conv2o = ws + 3932160;       //   196,608  (32,24,16,16)
    float* conv3o = ws + 4128768;       //    49,152  (32,24,8,8)
    float* stats  = ws + 4177920;       //       192
    float* qf     = ws + 4178112;       //     4,096  (32,128)
    unsigned short* Wbf = (unsigned short*)(ws + 4182208);  // 196,608 bf16
    // overlay into conv0o region (dead after conv1 consumes it):
    float* Abuf   = ws;                 //   524,288  (32,64,256)
    float* Bbuf   = ws + 524288;        //   524,288
    float* QTb    = ws + 1048576;       //     8,192  (32,256)
    float* part   = ws + 1155072;       //   262,144  (1024,256)

    hipMemsetAsync(stats, 0, 192 * sizeof(float), stream);

    // lstm (32 blocks) + conv0 (512) + gsW->bf16 cvt (96)
    fused_front<<<640, 512, 0, stream>>>(questions, embW, Wih, Whh, bih, bhh, qf,
                                         images, c0W, c0b, conv0o, stats, gsW, Wbf);
    // conv1: BN0 applied on load; out (32,24,32,32)
    conv_tiled<24, 8, true><<<512, 256, 0, stream>>>(
        conv0o, csW, csb, stats, bn0g, bn0b, 1.f / 131072.f,
        conv1o, stats + 48, 64, 64, 32, 32, 4);
    // conv2: out (32,24,16,16)
    conv_tiled<24, 8, true><<<128, 256, 0, stream>>>(
        conv1o, csW + 5184, csb + 24, stats + 48, bnsg, bnsb, 1.f / 32768.f,
        conv2o, stats + 96, 32, 32, 16, 16, 2);
    // conv3: out (32,24,8,8)
    conv_tiled<24, 8, true><<<32, 256, 0, stream>>>(
        conv2o, csW + 10368, csb + 48, stats + 96, bnsg + 24, bnsb + 24, 1.f / 8192.f,
        conv3o, stats + 144, 16, 16, 8, 8, 1);

    abqt_kernel<<<128, 256, 0, stream>>>(conv3o, stats + 144, bnsg + 48, bnsb + 48,
                                         1.f / 2048.f, qf, g0W, g0b, Abuf, Bbuf, QTb);
    gs_fused<<<1024, 256, 0, stream>>>(Abuf, Bbuf, QTb, Wbf, gsb, part);
    f_mlp<<<32, 256, 0, stream>>>(part, f0W, f0b, f1W, f1b, f2W, f2b, out);
}